// Round 6
// baseline (528.292 us; speedup 1.0000x reference)
//
#include <hip/hip_runtime.h>
#include <math.h>

#define NN 100000
#define NE 1600000
#define NETOT (NE + NN)
#define FIN 128
#define H1N 8
#define D1 64
#define NC 40
#define LNT 64                        // nodes per tile in lin kernels

#define BSH 9                         // 512 dst nodes per bucket
#define BNODES 512
#define NBUC ((NN + BNODES - 1) / BNODES)   // 196
#define NGRP 8                        // writer groups (XCD classes)
#define SUBCAP 1536                   // mean 1024, +16 sigma

__device__ __forceinline__ float leakyf(float x) { return x >= 0.0f ? x : 0.2f * x; }
__device__ __forceinline__ float eluf(float x)   { return x > 0.0f ? x : expm1f(x); }

// ---- edge_index dtype detection (int64 vs int32) ------------------------
__global__ void k_detect(const long long* __restrict__ ei, int* __restrict__ flag) {
  if (blockIdx.x == 0 && threadIdx.x == 0) {
    int is64 = 1;
    for (int i = 0; i < 16; ++i) {
      long long v = ei[i];
      if (v < 0 || v >= NN) is64 = 0;
    }
    *flag = is64;
  }
}

// ---- pass A: bucket-scatter edges by dst>>9 into per-(bucket,grp) bufs ---
// grp = blockIdx&7 tracks the XCD round-robin so each sub-buffer is written
// by one XCD class -> lines fill densely in one L2, single writeback.
// payload = (src<<9) | (dst&511): 4B per edge.
__global__ void k_passA(const void* __restrict__ ei, const int* __restrict__ flag,
                        unsigned int* __restrict__ subbuf, int* __restrict__ bcnt) {
  int e = blockIdx.x * 256 + threadIdx.x;
  if (e >= NE) return;
  int s, d;
  if (*flag) {
    const long long* p = (const long long*)ei;
    s = (int)p[e]; d = (int)p[NE + e];
  } else {
    const int* p = (const int*)ei;
    s = p[e]; d = p[NE + e];
  }
  int slot = (d >> BSH) * NGRP + (blockIdx.x & (NGRP - 1));
  int pos = atomicAdd(&bcnt[slot], 1);
  if (pos < SUBCAP)
    subbuf[(size_t)slot * SUBCAP + pos] = ((unsigned)s << BSH) | (unsigned)(d & (BNODES - 1));
}

// ---- bucket totals -> exclusive scan -> bucket_base (one small block) ----
__global__ void k_bucketsum(const int* __restrict__ bcnt, int* __restrict__ bucket_base,
                            int* __restrict__ row_start) {
  __shared__ int sh[256];
  int t = threadIdx.x;
  int tot = 0;
  if (t < NBUC) {
    int d0 = t << BSH;
    int nloc = min(BNODES, NN - d0);
    tot = nloc;                                   // self-loops
    for (int g = 0; g < NGRP; ++g) tot += min(bcnt[t * NGRP + g], SUBCAP);
  }
  sh[t] = tot;
  __syncthreads();
  for (int s = 1; s < 256; s <<= 1) {
    int x = (t >= s) ? sh[t - s] : 0;
    __syncthreads();
    sh[t] += x;
    __syncthreads();
  }
  if (t < NBUC) bucket_base[t] = sh[t] - tot;
  if (t == NBUC - 1) row_start[NN] = sh[t];
}

// ---- pass B: per-bucket LDS hist -> scan -> row_start + exact placement --
// csr writes land in this block's private ~35KB region: dense, one writeback.
__global__ __launch_bounds__(256) void k_passB(const int* __restrict__ bcnt,
                       const unsigned int* __restrict__ subbuf,
                       const int* __restrict__ bucket_base,
                       int* __restrict__ row_start, int* __restrict__ csr) {
  __shared__ int hist[BNODES];
  __shared__ int ps[256];
  __shared__ int cur[BNODES];
  int b = blockIdx.x, t = threadIdx.x;
  int d0 = b << BSH;
  int nloc = min(BNODES, NN - d0);
  hist[t] = 0; hist[t + 256] = 0;
  __syncthreads();
  for (int g = 0; g < NGRP; ++g) {
    int slot = b * NGRP + g;
    int cnt = min(bcnt[slot], SUBCAP);
    const unsigned int* sb = subbuf + (size_t)slot * SUBCAP;
    for (int i = t; i < cnt; i += 256)
      atomicAdd(&hist[sb[i] & (BNODES - 1)], 1);
  }
  __syncthreads();
  int j0 = 2 * t, j1 = 2 * t + 1;
  int s0 = (j0 < nloc) ? hist[j0] + 1 : 0;        // +1 self-loop
  int s1 = (j1 < nloc) ? hist[j1] + 1 : 0;
  int pairsum = s0 + s1;
  ps[t] = pairsum;
  __syncthreads();
  for (int s = 1; s < 256; s <<= 1) {
    int x = (t >= s) ? ps[t - s] : 0;
    __syncthreads();
    ps[t] += x;
    __syncthreads();
  }
  int excl = ps[t] - pairsum + bucket_base[b];
  if (j0 < nloc) {
    row_start[d0 + j0] = excl;
    csr[excl] = d0 + j0;                           // self-loop first
    cur[j0] = excl + 1;
  }
  if (j1 < nloc) {
    int rs = excl + s0;
    row_start[d0 + j1] = rs;
    csr[rs] = d0 + j1;
    cur[j1] = rs + 1;
  }
  __syncthreads();
  for (int g = 0; g < NGRP; ++g) {
    int slot = b * NGRP + g;
    int cnt = min(bcnt[slot], SUBCAP);
    const unsigned int* sb = subbuf + (size_t)slot * SUBCAP;
    for (int i = t; i < cnt; i += 256) {
      unsigned u = sb[i];
      int pos = atomicAdd(&cur[u & (BNODES - 1)], 1);
      csr[pos] = (int)(u >> BSH);
    }
  }
}

// ---- layer 1 linear: LDS-tiled GEMM h1 = x@W1 [N,64] + logits [N,8] ------
#define XS1(node, k) xs[(node) * FIN + ((k) ^ ((node) & 31))]
__global__ void k_lin1(const float* __restrict__ x, const float* __restrict__ W,
                       const float* __restrict__ aw_s, const float* __restrict__ aw_d,
                       float* __restrict__ h, float* __restrict__ als, float* __restrict__ ald) {
  __shared__ float ws[FIN * D1];
  __shared__ float xs[LNT * FIN];
  int t = threadIdx.x;
  int base = blockIdx.x * LNT;
  for (int i = t; i < FIN * D1; i += 256) ws[i] = W[i];
  for (int i = t; i < LNT * FIN; i += 256) {
    int node = i >> 7, k = i & 127;
    int gn = base + node;
    if (gn >= NN) gn = NN - 1;
    XS1(node, k) = x[(size_t)gn * FIN + k];
  }
  __syncthreads();
  int head = t & 7, ng = t >> 3;
  int n0l = ng * 2, n1l = n0l + 1;
  float acc0[8] = {0, 0, 0, 0, 0, 0, 0, 0};
  float acc1[8] = {0, 0, 0, 0, 0, 0, 0, 0};
  #pragma unroll 4
  for (int k = 0; k < FIN; ++k) {
    float x0 = XS1(n0l, k);
    float x1v = XS1(n1l, k);
    const float4* wr = (const float4*)&ws[k * D1 + head * 8];
    float4 wa = wr[0], wb = wr[1];
    acc0[0] = fmaf(x0, wa.x, acc0[0]); acc1[0] = fmaf(x1v, wa.x, acc1[0]);
    acc0[1] = fmaf(x0, wa.y, acc0[1]); acc1[1] = fmaf(x1v, wa.y, acc1[1]);
    acc0[2] = fmaf(x0, wa.z, acc0[2]); acc1[2] = fmaf(x1v, wa.z, acc1[2]);
    acc0[3] = fmaf(x0, wa.w, acc0[3]); acc1[3] = fmaf(x1v, wa.w, acc1[3]);
    acc0[4] = fmaf(x0, wb.x, acc0[4]); acc1[4] = fmaf(x1v, wb.x, acc1[4]);
    acc0[5] = fmaf(x0, wb.y, acc0[5]); acc1[5] = fmaf(x1v, wb.y, acc1[5]);
    acc0[6] = fmaf(x0, wb.z, acc0[6]); acc1[6] = fmaf(x1v, wb.z, acc1[6]);
    acc0[7] = fmaf(x0, wb.w, acc0[7]); acc1[7] = fmaf(x1v, wb.w, acc1[7]);
  }
  int n0 = base + n0l, n1 = base + n1l;
  float aws[8], awd[8];
  #pragma unroll
  for (int c = 0; c < 8; ++c) { aws[c] = aw_s[head * 8 + c]; awd[c] = aw_d[head * 8 + c]; }
  if (n0 < NN) {
    float s = 0.f, d = 0.f;
    #pragma unroll
    for (int c = 0; c < 8; ++c) {
      h[(size_t)n0 * D1 + head * 8 + c] = acc0[c];
      s = fmaf(acc0[c], aws[c], s);
      d = fmaf(acc0[c], awd[c], d);
    }
    als[n0 * H1N + head] = s;
    ald[n0 * H1N + head] = d;
  }
  if (n1 < NN) {
    float s = 0.f, d = 0.f;
    #pragma unroll
    for (int c = 0; c < 8; ++c) {
      h[(size_t)n1 * D1 + head * 8 + c] = acc1[c];
      s = fmaf(acc1[c], aws[c], s);
      d = fmaf(acc1[c], awd[c], d);
    }
    als[n1 * H1N + head] = s;
    ald[n1 * H1N + head] = d;
  }
}

// ---- layer 2 linear: LDS-tiled GEMM h2 = x1@W2 [N,40] + scalar logits ----
#define XS2(node, k) xs[(node) * D1 + ((k) ^ ((node) & 31))]
__global__ void k_lin2(const float* __restrict__ x, const float* __restrict__ W,
                       const float* __restrict__ aw_s, const float* __restrict__ aw_d,
                       float* __restrict__ h, float* __restrict__ als, float* __restrict__ ald) {
  __shared__ float ws[D1 * D1];
  __shared__ float xs[LNT * D1];
  int t = threadIdx.x;
  int base = blockIdx.x * LNT;
  for (int i = t; i < D1 * D1; i += 256) {
    int k = i >> 6, c = i & 63;
    ws[i] = (c < NC) ? W[k * NC + c] : 0.f;
  }
  for (int i = t; i < LNT * D1; i += 256) {
    int node = i >> 6, k = i & 63;
    int gn = base + node;
    if (gn >= NN) gn = NN - 1;
    XS2(node, k) = x[(size_t)gn * D1 + k];
  }
  __syncthreads();
  int g = t & 7, ng = t >> 3;
  int n0l = ng * 2, n1l = n0l + 1;
  float acc0[8] = {0, 0, 0, 0, 0, 0, 0, 0};
  float acc1[8] = {0, 0, 0, 0, 0, 0, 0, 0};
  #pragma unroll 4
  for (int k = 0; k < D1; ++k) {
    float x0 = XS2(n0l, k);
    float x1v = XS2(n1l, k);
    const float4* wr = (const float4*)&ws[k * D1 + g * 8];
    float4 wa = wr[0], wb = wr[1];
    acc0[0] = fmaf(x0, wa.x, acc0[0]); acc1[0] = fmaf(x1v, wa.x, acc1[0]);
    acc0[1] = fmaf(x0, wa.y, acc0[1]); acc1[1] = fmaf(x1v, wa.y, acc1[1]);
    acc0[2] = fmaf(x0, wa.z, acc0[2]); acc1[2] = fmaf(x1v, wa.z, acc1[2]);
    acc0[3] = fmaf(x0, wa.w, acc0[3]); acc1[3] = fmaf(x1v, wa.w, acc1[3]);
    acc0[4] = fmaf(x0, wb.x, acc0[4]); acc1[4] = fmaf(x1v, wb.x, acc1[4]);
    acc0[5] = fmaf(x0, wb.y, acc0[5]); acc1[5] = fmaf(x1v, wb.y, acc1[5]);
    acc0[6] = fmaf(x0, wb.z, acc0[6]); acc1[6] = fmaf(x1v, wb.z, acc1[6]);
    acc0[7] = fmaf(x0, wb.w, acc0[7]); acc1[7] = fmaf(x1v, wb.w, acc1[7]);
  }
  int n0 = base + n0l, n1 = base + n1l;
  float aws[8], awd[8];
  #pragma unroll
  for (int c = 0; c < 8; ++c) {
    int col = g * 8 + c;
    aws[c] = (col < NC) ? aw_s[col] : 0.f;
    awd[c] = (col < NC) ? aw_d[col] : 0.f;
  }
  float s0 = 0.f, d0 = 0.f, s1 = 0.f, d1 = 0.f;
  #pragma unroll
  for (int c = 0; c < 8; ++c) {
    s0 = fmaf(acc0[c], aws[c], s0); d0 = fmaf(acc0[c], awd[c], d0);
    s1 = fmaf(acc1[c], aws[c], s1); d1 = fmaf(acc1[c], awd[c], d1);
  }
  s0 += __shfl_xor(s0, 1); d0 += __shfl_xor(d0, 1); s1 += __shfl_xor(s1, 1); d1 += __shfl_xor(d1, 1);
  s0 += __shfl_xor(s0, 2); d0 += __shfl_xor(d0, 2); s1 += __shfl_xor(s1, 2); d1 += __shfl_xor(d1, 2);
  s0 += __shfl_xor(s0, 4); d0 += __shfl_xor(d0, 4); s1 += __shfl_xor(s1, 4); d1 += __shfl_xor(d1, 4);
  if (n0 < NN && g < 5) {
    #pragma unroll
    for (int c = 0; c < 8; ++c) h[(size_t)n0 * NC + g * 8 + c] = acc0[c];
  }
  if (n1 < NN && g < 5) {
    #pragma unroll
    for (int c = 0; c < 8; ++c) h[(size_t)n1 * NC + g * 8 + c] = acc1[c];
  }
  if (g == 0) {
    if (n0 < NN) { als[n0] = s0; ald[n0] = d0; }
    if (n1 < NN) { als[n1] = s1; ald[n1] = d1; }
  }
}

// ---- layer 1 fused single-pass aggregate, chunked wave-parallel ----------
__global__ void k_node1(const int* __restrict__ row_start, const int* __restrict__ csr,
                        const float* __restrict__ h, const float* __restrict__ als,
                        const float* __restrict__ ald, const float* __restrict__ b,
                        float* __restrict__ x1) {
  __shared__ float pl[4][64 * 9];
  int wid = threadIdx.x >> 6, lane = threadIdx.x & 63;
  int n = blockIdx.x * 4 + wid;
  if (n >= NN) return;
  float* pw = pl[wid];
  int r0 = row_start[n], r1 = row_start[n + 1];
  int hd = lane >> 3;
  const float4* adp = (const float4*)(ald + (size_t)n * H1N);
  float4 ad0 = adp[0], ad1 = adp[1];
  float S = 0.f, acc0 = 0.f, acc1 = 0.f, acc2 = 0.f, acc3 = 0.f;
  for (int kb = r0; kb < r1; kb += 64) {
    int cnt = min(64, r1 - kb);
    if (lane < cnt) {
      int sk = csr[kb + lane];
      const float4* ap = (const float4*)(als + (size_t)sk * H1N);
      float4 a0 = ap[0], a1 = ap[1];
      pw[lane * 9 + 0] = __expf(leakyf(a0.x + ad0.x));
      pw[lane * 9 + 1] = __expf(leakyf(a0.y + ad0.y));
      pw[lane * 9 + 2] = __expf(leakyf(a0.z + ad0.z));
      pw[lane * 9 + 3] = __expf(leakyf(a0.w + ad0.w));
      pw[lane * 9 + 4] = __expf(leakyf(a1.x + ad1.x));
      pw[lane * 9 + 5] = __expf(leakyf(a1.y + ad1.y));
      pw[lane * 9 + 6] = __expf(leakyf(a1.z + ad1.z));
      pw[lane * 9 + 7] = __expf(leakyf(a1.w + ad1.w));
      pw[lane * 9 + 8] = __int_as_float(sk);
    }
    asm volatile("s_waitcnt lgkmcnt(0)" ::: "memory");   // wave-internal LDS RAW
    int j = 0;
    for (; j + 4 <= cnt; j += 4) {
      int s0 = __float_as_int(pw[(j + 0) * 9 + 8]);
      int s1 = __float_as_int(pw[(j + 1) * 9 + 8]);
      int s2 = __float_as_int(pw[(j + 2) * 9 + 8]);
      int s3 = __float_as_int(pw[(j + 3) * 9 + 8]);
      float p0 = pw[(j + 0) * 9 + hd], p1 = pw[(j + 1) * 9 + hd];
      float p2 = pw[(j + 2) * 9 + hd], p3 = pw[(j + 3) * 9 + hd];
      float g0 = h[(size_t)s0 * D1 + lane];
      float g1 = h[(size_t)s1 * D1 + lane];
      float g2 = h[(size_t)s2 * D1 + lane];
      float g3 = h[(size_t)s3 * D1 + lane];
      acc0 = fmaf(p0, g0, acc0);
      acc1 = fmaf(p1, g1, acc1);
      acc2 = fmaf(p2, g2, acc2);
      acc3 = fmaf(p3, g3, acc3);
      S += (p0 + p1) + (p2 + p3);
    }
    for (; j < cnt; ++j) {
      int s0 = __float_as_int(pw[j * 9 + 8]);
      float p0 = pw[j * 9 + hd];
      acc0 = fmaf(p0, h[(size_t)s0 * D1 + lane], acc0);
      S += p0;
    }
  }
  float acc = (acc0 + acc1) + (acc2 + acc3);
  x1[(size_t)n * D1 + lane] = eluf(acc / (S + 1e-16f) + b[lane]);
}

// ---- layer 2 fused single-pass aggregate, chunked wave-parallel ----------
__global__ void k_node2(const int* __restrict__ row_start, const int* __restrict__ csr,
                        const float* __restrict__ h, const float* __restrict__ als,
                        const float* __restrict__ ald, const float* __restrict__ b,
                        float* __restrict__ out) {
  __shared__ float pl[4][64 * 3];
  int wid = threadIdx.x >> 6, lane = threadIdx.x & 63;
  int n = blockIdx.x * 4 + wid;
  if (n >= NN) return;
  float* pw = pl[wid];
  int r0 = row_start[n], r1 = row_start[n + 1];
  int cl = lane < NC ? lane : NC - 1;
  float aldn = ald[n];
  float S = 0.f, acc0 = 0.f, acc1 = 0.f, acc2 = 0.f, acc3 = 0.f;
  for (int kb = r0; kb < r1; kb += 64) {
    int cnt = min(64, r1 - kb);
    if (lane < cnt) {
      int sk = csr[kb + lane];
      pw[lane * 3 + 0] = __expf(leakyf(als[sk] + aldn));
      pw[lane * 3 + 1] = __int_as_float(sk);
    }
    asm volatile("s_waitcnt lgkmcnt(0)" ::: "memory");
    int j = 0;
    for (; j + 4 <= cnt; j += 4) {
      int s0 = __float_as_int(pw[(j + 0) * 3 + 1]);
      int s1 = __float_as_int(pw[(j + 1) * 3 + 1]);
      int s2 = __float_as_int(pw[(j + 2) * 3 + 1]);
      int s3 = __float_as_int(pw[(j + 3) * 3 + 1]);
      float p0 = pw[(j + 0) * 3], p1 = pw[(j + 1) * 3];
      float p2 = pw[(j + 2) * 3], p3 = pw[(j + 3) * 3];
      float g0 = h[(size_t)s0 * NC + cl];
      float g1 = h[(size_t)s1 * NC + cl];
      float g2 = h[(size_t)s2 * NC + cl];
      float g3 = h[(size_t)s3 * NC + cl];
      acc0 = fmaf(p0, g0, acc0);
      acc1 = fmaf(p1, g1, acc1);
      acc2 = fmaf(p2, g2, acc2);
      acc3 = fmaf(p3, g3, acc3);
      S += (p0 + p1) + (p2 + p3);
    }
    for (; j < cnt; ++j) {
      int s0 = __float_as_int(pw[j * 3 + 1]);
      float p0 = pw[j * 3];
      acc0 = fmaf(p0, h[(size_t)s0 * NC + cl], acc0);
      S += p0;
    }
  }
  float acc = (acc0 + acc1) + (acc2 + acc3);
  if (lane < NC) out[(size_t)n * NC + lane] = eluf(acc / (S + 1e-16f) + b[lane]);
}

extern "C" void kernel_launch(void* const* d_in, const int* in_sizes, int n_in,
                              void* d_out, int out_size, void* d_ws, size_t ws_size,
                              hipStream_t stream) {
  const float* x    = (const float*)d_in[0];
  const void*  ei   = d_in[1];
  const float* W1   = (const float*)d_in[3];
  const float* as1w = (const float*)d_in[4];
  const float* ad1w = (const float*)d_in[5];
  const float* b1   = (const float*)d_in[6];
  const float* W2   = (const float*)d_in[7];
  const float* as2w = (const float*)d_in[8];
  const float* ad2w = (const float*)d_in[9];
  const float* b2   = (const float*)d_in[10];
  float* out = (float*)d_out;

  char* w = (char*)d_ws;
  size_t off = 0;
  auto carve = [&](size_t bytes) -> void* {
    void* r = w + off;
    off += (bytes + 255) & ~(size_t)255;
    return r;
  };
  int*          flag        = (int*)carve(256);
  int*          bcnt        = (int*)carve((size_t)NBUC * NGRP * 4);
  int*          bucket_base = (int*)carve((size_t)NBUC * 4);
  unsigned int* subbuf      = (unsigned int*)carve((size_t)NBUC * NGRP * SUBCAP * 4);
  int*          row_start   = (int*)carve((size_t)(NN + 1) * 4);
  int*          csr         = (int*)carve((size_t)NETOT * 4);
  float*        h1          = (float*)carve((size_t)NN * D1 * 4);   // reused as h2
  float*        als1        = (float*)carve((size_t)NN * H1N * 4);  // reused as als2
  float*        ald1        = (float*)carve((size_t)NN * H1N * 4);  // reused as ald2
  float*        x1          = (float*)carve((size_t)NN * D1 * 4);
  float* h2 = h1; float* als2 = als1; float* ald2 = ald1;

  const int LB = (NN + LNT - 1) / LNT;

  // CSR build: detect -> bucket-scatter -> bucket scan -> per-bucket place
  k_detect<<<1, 64, 0, stream>>>((const long long*)ei, flag);
  hipMemsetAsync(bcnt, 0, (size_t)NBUC * NGRP * 4, stream);
  k_passA<<<(NE + 255) / 256, 256, 0, stream>>>(ei, flag, subbuf, bcnt);
  k_bucketsum<<<1, 256, 0, stream>>>(bcnt, bucket_base, row_start);
  k_passB<<<NBUC, 256, 0, stream>>>(bcnt, subbuf, bucket_base, row_start, csr);

  // layer 1
  k_lin1<<<LB, 256, 0, stream>>>(x, W1, as1w, ad1w, h1, als1, ald1);
  k_node1<<<NN / 4, 256, 0, stream>>>(row_start, csr, h1, als1, ald1, b1, x1);

  // layer 2
  k_lin2<<<LB, 256, 0, stream>>>(x1, W2, as2w, ad2w, h2, als2, ald2);
  k_node2<<<NN / 4, 256, 0, stream>>>(row_start, csr, h2, als2, ald2, b2, out);
}

// Round 7
// 267.451 us; speedup vs baseline: 1.9753x; 1.9753x over previous
//
#include <hip/hip_runtime.h>
#include <math.h>

#define NN 100000
#define NE 1600000
#define NETOT (NE + NN)
#define FIN 128
#define H1N 8
#define D1 64
#define NC 40
#define LNT 64                        // nodes per tile in lin kernels

#define BSH 9                         // 512 dst nodes per bucket
#define BNODES 512
#define NBUC ((NN + BNODES - 1) / BNODES)   // 196
#define EPB 4096                      // edges per passA block
#define NBLKA ((NE + EPB - 1) / EPB)  // 391
#define BCAP 9216                     // per-bucket edge capacity (mean 8192, +11 sigma)

__device__ __forceinline__ float leakyf(float x) { return x >= 0.0f ? x : 0.2f * x; }
__device__ __forceinline__ float eluf(float x)   { return x > 0.0f ? x : expm1f(x); }

// ---- edge_index dtype detection (int64 vs int32) ------------------------
__global__ void k_detect(const long long* __restrict__ ei, int* __restrict__ flag) {
  if (blockIdx.x == 0 && threadIdx.x == 0) {
    int is64 = 1;
    for (int i = 0; i < 16; ++i) {
      long long v = ei[i];
      if (v < 0 || v >= NN) is64 = 0;
    }
    *flag = is64;
  }
}

// ---- pass A: block-local LDS counting sort by bucket, coalesced write ----
// No hot global atomics: LDS hist + LDS cursors; one global atomicAdd per
// (block, non-empty bucket) to reserve space (<=391 per bucket address).
// payload = (src<<9) | (dst&511).
__global__ __launch_bounds__(256) void k_passA(const void* __restrict__ ei,
                        const int* __restrict__ flag,
                        unsigned int* __restrict__ subbuf, int* __restrict__ bcnt) {
  __shared__ unsigned int   pay[EPB];
  __shared__ unsigned short bk[EPB];
  __shared__ unsigned int   spay[EPB];
  __shared__ unsigned short sbk[EPB];
  __shared__ int hist[256];
  __shared__ int lstart[256];
  __shared__ int cur[256];
  __shared__ int gbase[256];
  int t = threadIdx.x;
  int e0 = blockIdx.x * EPB;
  int cnt = min(EPB, NE - e0);
  hist[t] = 0;
  __syncthreads();
  bool f64 = (*flag) != 0;
  for (int i = t; i < cnt; i += 256) {
    int s, d;
    if (f64) {
      const long long* p = (const long long*)ei;
      s = (int)p[e0 + i]; d = (int)p[NE + e0 + i];
    } else {
      const int* p = (const int*)ei;
      s = p[e0 + i]; d = p[NE + e0 + i];
    }
    int b = d >> BSH;
    pay[i] = ((unsigned)s << BSH) | (unsigned)(d & (BNODES - 1));
    bk[i] = (unsigned short)b;
    atomicAdd(&hist[b], 1);
  }
  __syncthreads();
  // exclusive scan of hist (Hillis-Steele over 256)
  int v = hist[t];
  lstart[t] = v;
  __syncthreads();
  for (int st = 1; st < 256; st <<= 1) {
    int xv = (t >= st) ? lstart[t - st] : 0;
    __syncthreads();
    lstart[t] += xv;
    __syncthreads();
  }
  int excl = lstart[t] - v;
  __syncthreads();
  lstart[t] = excl;
  cur[t] = excl;
  gbase[t] = (v > 0) ? atomicAdd(&bcnt[t], v) : 0;
  __syncthreads();
  // counting-sort into bucket-contiguous LDS order
  for (int i = t; i < cnt; i += 256) {
    int b = bk[i];
    int pos = atomicAdd(&cur[b], 1);
    spay[pos] = pay[i];
    sbk[pos] = (unsigned short)b;
  }
  __syncthreads();
  // write out: consecutive i within a bucket run -> consecutive global addrs
  for (int i = t; i < cnt; i += 256) {
    int b = sbk[i];
    int o = gbase[b] + (i - lstart[b]);
    if (o < BCAP) subbuf[(size_t)b * BCAP + o] = spay[i];
  }
}

// ---- bucket totals -> exclusive scan -> bucket_base (one small block) ----
__global__ void k_bucketsum(const int* __restrict__ bcnt, int* __restrict__ bucket_base,
                            int* __restrict__ row_start) {
  __shared__ int sh[256];
  int t = threadIdx.x;
  int tot = 0;
  if (t < NBUC) {
    int d0 = t << BSH;
    int nloc = min(BNODES, NN - d0);
    tot = nloc + min(bcnt[t], BCAP);              // self-loops + edges
  }
  sh[t] = tot;
  __syncthreads();
  for (int s = 1; s < 256; s <<= 1) {
    int x = (t >= s) ? sh[t - s] : 0;
    __syncthreads();
    sh[t] += x;
    __syncthreads();
  }
  if (t < NBUC) bucket_base[t] = sh[t] - tot;
  if (t == NBUC - 1) row_start[NN] = sh[t];
}

// ---- pass B: per-bucket LDS hist -> scan -> row_start + exact placement --
__global__ __launch_bounds__(256) void k_passB(const int* __restrict__ bcnt,
                       const unsigned int* __restrict__ subbuf,
                       const int* __restrict__ bucket_base,
                       int* __restrict__ row_start, int* __restrict__ csr) {
  __shared__ int hist[BNODES];
  __shared__ int ps[256];
  __shared__ int cur[BNODES];
  int b = blockIdx.x, t = threadIdx.x;
  int d0 = b << BSH;
  int nloc = min(BNODES, NN - d0);
  hist[t] = 0; hist[t + 256] = 0;
  __syncthreads();
  int cnt = min(bcnt[b], BCAP);
  const unsigned int* sb = subbuf + (size_t)b * BCAP;
  for (int i = t; i < cnt; i += 256)
    atomicAdd(&hist[sb[i] & (BNODES - 1)], 1);
  __syncthreads();
  int j0 = 2 * t, j1 = 2 * t + 1;
  int s0 = (j0 < nloc) ? hist[j0] + 1 : 0;        // +1 self-loop
  int s1 = (j1 < nloc) ? hist[j1] + 1 : 0;
  int pairsum = s0 + s1;
  ps[t] = pairsum;
  __syncthreads();
  for (int s = 1; s < 256; s <<= 1) {
    int x = (t >= s) ? ps[t - s] : 0;
    __syncthreads();
    ps[t] += x;
    __syncthreads();
  }
  int excl = ps[t] - pairsum + bucket_base[b];
  if (j0 < nloc) {
    row_start[d0 + j0] = excl;
    csr[excl] = d0 + j0;                           // self-loop first
    cur[j0] = excl + 1;
  }
  if (j1 < nloc) {
    int rs = excl + s0;
    row_start[d0 + j1] = rs;
    csr[rs] = d0 + j1;
    cur[j1] = rs + 1;
  }
  __syncthreads();
  for (int i = t; i < cnt; i += 256) {
    unsigned u = sb[i];
    int pos = atomicAdd(&cur[u & (BNODES - 1)], 1);
    csr[pos] = (int)(u >> BSH);
  }
}

// ---- layer 1 linear: LDS-tiled GEMM h1 = x@W1 [N,64] + logits [N,8] ------
#define XS1(node, k) xs[(node) * FIN + ((k) ^ ((node) & 31))]
__global__ void k_lin1(const float* __restrict__ x, const float* __restrict__ W,
                       const float* __restrict__ aw_s, const float* __restrict__ aw_d,
                       float* __restrict__ h, float* __restrict__ als, float* __restrict__ ald) {
  __shared__ float ws[FIN * D1];
  __shared__ float xs[LNT * FIN];
  int t = threadIdx.x;
  int base = blockIdx.x * LNT;
  for (int i = t; i < FIN * D1; i += 256) ws[i] = W[i];
  for (int i = t; i < LNT * FIN; i += 256) {
    int node = i >> 7, k = i & 127;
    int gn = base + node;
    if (gn >= NN) gn = NN - 1;
    XS1(node, k) = x[(size_t)gn * FIN + k];
  }
  __syncthreads();
  int head = t & 7, ng = t >> 3;
  int n0l = ng * 2, n1l = n0l + 1;
  float acc0[8] = {0, 0, 0, 0, 0, 0, 0, 0};
  float acc1[8] = {0, 0, 0, 0, 0, 0, 0, 0};
  #pragma unroll 4
  for (int k = 0; k < FIN; ++k) {
    float x0 = XS1(n0l, k);
    float x1v = XS1(n1l, k);
    const float4* wr = (const float4*)&ws[k * D1 + head * 8];
    float4 wa = wr[0], wb = wr[1];
    acc0[0] = fmaf(x0, wa.x, acc0[0]); acc1[0] = fmaf(x1v, wa.x, acc1[0]);
    acc0[1] = fmaf(x0, wa.y, acc0[1]); acc1[1] = fmaf(x1v, wa.y, acc1[1]);
    acc0[2] = fmaf(x0, wa.z, acc0[2]); acc1[2] = fmaf(x1v, wa.z, acc1[2]);
    acc0[3] = fmaf(x0, wa.w, acc0[3]); acc1[3] = fmaf(x1v, wa.w, acc1[3]);
    acc0[4] = fmaf(x0, wb.x, acc0[4]); acc1[4] = fmaf(x1v, wb.x, acc1[4]);
    acc0[5] = fmaf(x0, wb.y, acc0[5]); acc1[5] = fmaf(x1v, wb.y, acc1[5]);
    acc0[6] = fmaf(x0, wb.z, acc0[6]); acc1[6] = fmaf(x1v, wb.z, acc1[6]);
    acc0[7] = fmaf(x0, wb.w, acc0[7]); acc1[7] = fmaf(x1v, wb.w, acc1[7]);
  }
  int n0 = base + n0l, n1 = base + n1l;
  float aws[8], awd[8];
  #pragma unroll
  for (int c = 0; c < 8; ++c) { aws[c] = aw_s[head * 8 + c]; awd[c] = aw_d[head * 8 + c]; }
  if (n0 < NN) {
    float s = 0.f, d = 0.f;
    #pragma unroll
    for (int c = 0; c < 8; ++c) {
      h[(size_t)n0 * D1 + head * 8 + c] = acc0[c];
      s = fmaf(acc0[c], aws[c], s);
      d = fmaf(acc0[c], awd[c], d);
    }
    als[n0 * H1N + head] = s;
    ald[n0 * H1N + head] = d;
  }
  if (n1 < NN) {
    float s = 0.f, d = 0.f;
    #pragma unroll
    for (int c = 0; c < 8; ++c) {
      h[(size_t)n1 * D1 + head * 8 + c] = acc1[c];
      s = fmaf(acc1[c], aws[c], s);
      d = fmaf(acc1[c], awd[c], d);
    }
    als[n1 * H1N + head] = s;
    ald[n1 * H1N + head] = d;
  }
}

// ---- layer 2 linear: LDS-tiled GEMM h2 = x1@W2 [N,40] + scalar logits ----
#define XS2(node, k) xs[(node) * D1 + ((k) ^ ((node) & 31))]
__global__ void k_lin2(const float* __restrict__ x, const float* __restrict__ W,
                       const float* __restrict__ aw_s, const float* __restrict__ aw_d,
                       float* __restrict__ h, float* __restrict__ als, float* __restrict__ ald) {
  __shared__ float ws[D1 * D1];
  __shared__ float xs[LNT * D1];
  int t = threadIdx.x;
  int base = blockIdx.x * LNT;
  for (int i = t; i < D1 * D1; i += 256) {
    int k = i >> 6, c = i & 63;
    ws[i] = (c < NC) ? W[k * NC + c] : 0.f;
  }
  for (int i = t; i < LNT * D1; i += 256) {
    int node = i >> 6, k = i & 63;
    int gn = base + node;
    if (gn >= NN) gn = NN - 1;
    XS2(node, k) = x[(size_t)gn * D1 + k];
  }
  __syncthreads();
  int g = t & 7, ng = t >> 3;
  int n0l = ng * 2, n1l = n0l + 1;
  float acc0[8] = {0, 0, 0, 0, 0, 0, 0, 0};
  float acc1[8] = {0, 0, 0, 0, 0, 0, 0, 0};
  #pragma unroll 4
  for (int k = 0; k < D1; ++k) {
    float x0 = XS2(n0l, k);
    float x1v = XS2(n1l, k);
    const float4* wr = (const float4*)&ws[k * D1 + g * 8];
    float4 wa = wr[0], wb = wr[1];
    acc0[0] = fmaf(x0, wa.x, acc0[0]); acc1[0] = fmaf(x1v, wa.x, acc1[0]);
    acc0[1] = fmaf(x0, wa.y, acc0[1]); acc1[1] = fmaf(x1v, wa.y, acc1[1]);
    acc0[2] = fmaf(x0, wa.z, acc0[2]); acc1[2] = fmaf(x1v, wa.z, acc1[2]);
    acc0[3] = fmaf(x0, wa.w, acc0[3]); acc1[3] = fmaf(x1v, wa.w, acc1[3]);
    acc0[4] = fmaf(x0, wb.x, acc0[4]); acc1[4] = fmaf(x1v, wb.x, acc1[4]);
    acc0[5] = fmaf(x0, wb.y, acc0[5]); acc1[5] = fmaf(x1v, wb.y, acc1[5]);
    acc0[6] = fmaf(x0, wb.z, acc0[6]); acc1[6] = fmaf(x1v, wb.z, acc1[6]);
    acc0[7] = fmaf(x0, wb.w, acc0[7]); acc1[7] = fmaf(x1v, wb.w, acc1[7]);
  }
  int n0 = base + n0l, n1 = base + n1l;
  float aws[8], awd[8];
  #pragma unroll
  for (int c = 0; c < 8; ++c) {
    int col = g * 8 + c;
    aws[c] = (col < NC) ? aw_s[col] : 0.f;
    awd[c] = (col < NC) ? aw_d[col] : 0.f;
  }
  float s0 = 0.f, d0 = 0.f, s1 = 0.f, d1 = 0.f;
  #pragma unroll
  for (int c = 0; c < 8; ++c) {
    s0 = fmaf(acc0[c], aws[c], s0); d0 = fmaf(acc0[c], awd[c], d0);
    s1 = fmaf(acc1[c], aws[c], s1); d1 = fmaf(acc1[c], awd[c], d1);
  }
  s0 += __shfl_xor(s0, 1); d0 += __shfl_xor(d0, 1); s1 += __shfl_xor(s1, 1); d1 += __shfl_xor(d1, 1);
  s0 += __shfl_xor(s0, 2); d0 += __shfl_xor(d0, 2); s1 += __shfl_xor(s1, 2); d1 += __shfl_xor(d1, 2);
  s0 += __shfl_xor(s0, 4); d0 += __shfl_xor(d0, 4); s1 += __shfl_xor(s1, 4); d1 += __shfl_xor(d1, 4);
  if (n0 < NN && g < 5) {
    #pragma unroll
    for (int c = 0; c < 8; ++c) h[(size_t)n0 * NC + g * 8 + c] = acc0[c];
  }
  if (n1 < NN && g < 5) {
    #pragma unroll
    for (int c = 0; c < 8; ++c) h[(size_t)n1 * NC + g * 8 + c] = acc1[c];
  }
  if (g == 0) {
    if (n0 < NN) { als[n0] = s0; ald[n0] = d0; }
    if (n1 < NN) { als[n1] = s1; ald[n1] = d1; }
  }
}

// ---- layer 1 fused single-pass aggregate, chunked wave-parallel ----------
__global__ void k_node1(const int* __restrict__ row_start, const int* __restrict__ csr,
                        const float* __restrict__ h, const float* __restrict__ als,
                        const float* __restrict__ ald, const float* __restrict__ b,
                        float* __restrict__ x1) {
  __shared__ float pl[4][64 * 9];
  int wid = threadIdx.x >> 6, lane = threadIdx.x & 63;
  int n = blockIdx.x * 4 + wid;
  if (n >= NN) return;
  float* pw = pl[wid];
  int r0 = row_start[n], r1 = row_start[n + 1];
  int hd = lane >> 3;
  const float4* adp = (const float4*)(ald + (size_t)n * H1N);
  float4 ad0 = adp[0], ad1 = adp[1];
  float S = 0.f, acc0 = 0.f, acc1 = 0.f, acc2 = 0.f, acc3 = 0.f;
  for (int kb = r0; kb < r1; kb += 64) {
    int cnt = min(64, r1 - kb);
    if (lane < cnt) {
      int sk = csr[kb + lane];
      const float4* ap = (const float4*)(als + (size_t)sk * H1N);
      float4 a0 = ap[0], a1 = ap[1];
      pw[lane * 9 + 0] = __expf(leakyf(a0.x + ad0.x));
      pw[lane * 9 + 1] = __expf(leakyf(a0.y + ad0.y));
      pw[lane * 9 + 2] = __expf(leakyf(a0.z + ad0.z));
      pw[lane * 9 + 3] = __expf(leakyf(a0.w + ad0.w));
      pw[lane * 9 + 4] = __expf(leakyf(a1.x + ad1.x));
      pw[lane * 9 + 5] = __expf(leakyf(a1.y + ad1.y));
      pw[lane * 9 + 6] = __expf(leakyf(a1.z + ad1.z));
      pw[lane * 9 + 7] = __expf(leakyf(a1.w + ad1.w));
      pw[lane * 9 + 8] = __int_as_float(sk);
    }
    asm volatile("s_waitcnt lgkmcnt(0)" ::: "memory");   // wave-internal LDS RAW
    int j = 0;
    for (; j + 4 <= cnt; j += 4) {
      int s0 = __float_as_int(pw[(j + 0) * 9 + 8]);
      int s1 = __float_as_int(pw[(j + 1) * 9 + 8]);
      int s2 = __float_as_int(pw[(j + 2) * 9 + 8]);
      int s3 = __float_as_int(pw[(j + 3) * 9 + 8]);
      float p0 = pw[(j + 0) * 9 + hd], p1 = pw[(j + 1) * 9 + hd];
      float p2 = pw[(j + 2) * 9 + hd], p3 = pw[(j + 3) * 9 + hd];
      float g0 = h[(size_t)s0 * D1 + lane];
      float g1 = h[(size_t)s1 * D1 + lane];
      float g2 = h[(size_t)s2 * D1 + lane];
      float g3 = h[(size_t)s3 * D1 + lane];
      acc0 = fmaf(p0, g0, acc0);
      acc1 = fmaf(p1, g1, acc1);
      acc2 = fmaf(p2, g2, acc2);
      acc3 = fmaf(p3, g3, acc3);
      S += (p0 + p1) + (p2 + p3);
    }
    for (; j < cnt; ++j) {
      int s0 = __float_as_int(pw[j * 9 + 8]);
      float p0 = pw[j * 9 + hd];
      acc0 = fmaf(p0, h[(size_t)s0 * D1 + lane], acc0);
      S += p0;
    }
  }
  float acc = (acc0 + acc1) + (acc2 + acc3);
  x1[(size_t)n * D1 + lane] = eluf(acc / (S + 1e-16f) + b[lane]);
}

// ---- layer 2 fused single-pass aggregate, chunked wave-parallel ----------
__global__ void k_node2(const int* __restrict__ row_start, const int* __restrict__ csr,
                        const float* __restrict__ h, const float* __restrict__ als,
                        const float* __restrict__ ald, const float* __restrict__ b,
                        float* __restrict__ out) {
  __shared__ float pl[4][64 * 3];
  int wid = threadIdx.x >> 6, lane = threadIdx.x & 63;
  int n = blockIdx.x * 4 + wid;
  if (n >= NN) return;
  float* pw = pl[wid];
  int r0 = row_start[n], r1 = row_start[n + 1];
  int cl = lane < NC ? lane : NC - 1;
  float aldn = ald[n];
  float S = 0.f, acc0 = 0.f, acc1 = 0.f, acc2 = 0.f, acc3 = 0.f;
  for (int kb = r0; kb < r1; kb += 64) {
    int cnt = min(64, r1 - kb);
    if (lane < cnt) {
      int sk = csr[kb + lane];
      pw[lane * 3 + 0] = __expf(leakyf(als[sk] + aldn));
      pw[lane * 3 + 1] = __int_as_float(sk);
    }
    asm volatile("s_waitcnt lgkmcnt(0)" ::: "memory");
    int j = 0;
    for (; j + 4 <= cnt; j += 4) {
      int s0 = __float_as_int(pw[(j + 0) * 3 + 1]);
      int s1 = __float_as_int(pw[(j + 1) * 3 + 1]);
      int s2 = __float_as_int(pw[(j + 2) * 3 + 1]);
      int s3 = __float_as_int(pw[(j + 3) * 3 + 1]);
      float p0 = pw[(j + 0) * 3], p1 = pw[(j + 1) * 3];
      float p2 = pw[(j + 2) * 3], p3 = pw[(j + 3) * 3];
      float g0 = h[(size_t)s0 * NC + cl];
      float g1 = h[(size_t)s1 * NC + cl];
      float g2 = h[(size_t)s2 * NC + cl];
      float g3 = h[(size_t)s3 * NC + cl];
      acc0 = fmaf(p0, g0, acc0);
      acc1 = fmaf(p1, g1, acc1);
      acc2 = fmaf(p2, g2, acc2);
      acc3 = fmaf(p3, g3, acc3);
      S += (p0 + p1) + (p2 + p3);
    }
    for (; j < cnt; ++j) {
      int s0 = __float_as_int(pw[j * 3 + 1]);
      float p0 = pw[j * 3];
      acc0 = fmaf(p0, h[(size_t)s0 * NC + cl], acc0);
      S += p0;
    }
  }
  float acc = (acc0 + acc1) + (acc2 + acc3);
  if (lane < NC) out[(size_t)n * NC + lane] = eluf(acc / (S + 1e-16f) + b[lane]);
}

extern "C" void kernel_launch(void* const* d_in, const int* in_sizes, int n_in,
                              void* d_out, int out_size, void* d_ws, size_t ws_size,
                              hipStream_t stream) {
  const float* x    = (const float*)d_in[0];
  const void*  ei   = d_in[1];
  const float* W1   = (const float*)d_in[3];
  const float* as1w = (const float*)d_in[4];
  const float* ad1w = (const float*)d_in[5];
  const float* b1   = (const float*)d_in[6];
  const float* W2   = (const float*)d_in[7];
  const float* as2w = (const float*)d_in[8];
  const float* ad2w = (const float*)d_in[9];
  const float* b2   = (const float*)d_in[10];
  float* out = (float*)d_out;

  char* w = (char*)d_ws;
  size_t off = 0;
  auto carve = [&](size_t bytes) -> void* {
    void* r = w + off;
    off += (bytes + 255) & ~(size_t)255;
    return r;
  };
  int*          flag        = (int*)carve(256);
  int*          bcnt        = (int*)carve((size_t)NBUC * 4);
  int*          bucket_base = (int*)carve((size_t)NBUC * 4);
  unsigned int* subbuf      = (unsigned int*)carve((size_t)NBUC * BCAP * 4);
  int*          row_start   = (int*)carve((size_t)(NN + 1) * 4);
  int*          csr         = (int*)carve((size_t)NETOT * 4);
  float*        h1          = (float*)carve((size_t)NN * D1 * 4);   // reused as h2
  float*        als1        = (float*)carve((size_t)NN * H1N * 4);  // reused as als2
  float*        ald1        = (float*)carve((size_t)NN * H1N * 4);  // reused as ald2
  float*        x1          = (float*)carve((size_t)NN * D1 * 4);
  float* h2 = h1; float* als2 = als1; float* ald2 = ald1;

  const int LB = (NN + LNT - 1) / LNT;

  // CSR build: detect -> block-local sort+scatter -> bucket scan -> place
  k_detect<<<1, 64, 0, stream>>>((const long long*)ei, flag);
  hipMemsetAsync(bcnt, 0, (size_t)NBUC * 4, stream);
  k_passA<<<NBLKA, 256, 0, stream>>>(ei, flag, subbuf, bcnt);
  k_bucketsum<<<1, 256, 0, stream>>>(bcnt, bucket_base, row_start);
  k_passB<<<NBUC, 256, 0, stream>>>(bcnt, subbuf, bucket_base, row_start, csr);

  // layer 1
  k_lin1<<<LB, 256, 0, stream>>>(x, W1, as1w, ad1w, h1, als1, ald1);
  k_node1<<<NN / 4, 256, 0, stream>>>(row_start, csr, h1, als1, ald1, b1, x1);

  // layer 2
  k_lin2<<<LB, 256, 0, stream>>>(x1, W2, as2w, ad2w, h2, als2, ald2);
  k_node2<<<NN / 4, 256, 0, stream>>>(row_start, csr, h2, als2, ald2, b2, out);
}

// Round 8
// 243.424 us; speedup vs baseline: 2.1703x; 1.0987x over previous
//
#include <hip/hip_runtime.h>
#include <math.h>

#define NN 100000
#define NE 1600000
#define NETOT (NE + NN)
#define FIN 128
#define H1N 8
#define D1 64
#define NC 40
#define LNT 64                        // nodes per tile in lin kernels

#define BSH 9                         // 512 dst nodes per bucket
#define BNODES 512
#define NBUC ((NN + BNODES - 1) / BNODES)   // 196
#define EPB 4096                      // edges per passA block
#define NBLKA ((NE + EPB - 1) / EPB)  // 391
#define BCAP 9216                     // per-bucket edge capacity (mean 8192, +11 sigma)

__device__ __forceinline__ float leakyf(float x) { return x >= 0.0f ? x : 0.2f * x; }
__device__ __forceinline__ float eluf(float x)   { return x > 0.0f ? x : expm1f(x); }

// bf16 helpers (RNE pack, cheap unpack)
__device__ __forceinline__ unsigned short f2bf(float f) {
  unsigned u = __float_as_uint(f);
  u += 0x7fffu + ((u >> 16) & 1u);
  return (unsigned short)(u >> 16);
}
__device__ __forceinline__ float bf2f(unsigned short s) {
  return __uint_as_float((unsigned)s << 16);
}

// ---- edge_index dtype detection (int64 vs int32) ------------------------
__global__ void k_detect(const long long* __restrict__ ei, int* __restrict__ flag) {
  if (blockIdx.x == 0 && threadIdx.x == 0) {
    int is64 = 1;
    for (int i = 0; i < 16; ++i) {
      long long v = ei[i];
      if (v < 0 || v >= NN) is64 = 0;
    }
    *flag = is64;
  }
}

// ---- pass A: block-local LDS counting sort by bucket, coalesced write ----
__global__ __launch_bounds__(256) void k_passA(const void* __restrict__ ei,
                        const int* __restrict__ flag,
                        unsigned int* __restrict__ subbuf, int* __restrict__ bcnt) {
  __shared__ unsigned int   pay[EPB];
  __shared__ unsigned short bk[EPB];
  __shared__ unsigned int   spay[EPB];
  __shared__ unsigned short sbk[EPB];
  __shared__ int hist[256];
  __shared__ int lstart[256];
  __shared__ int cur[256];
  __shared__ int gbase[256];
  int t = threadIdx.x;
  int e0 = blockIdx.x * EPB;
  int cnt = min(EPB, NE - e0);
  hist[t] = 0;
  __syncthreads();
  bool f64 = (*flag) != 0;
  for (int i = t; i < cnt; i += 256) {
    int s, d;
    if (f64) {
      const long long* p = (const long long*)ei;
      s = (int)p[e0 + i]; d = (int)p[NE + e0 + i];
    } else {
      const int* p = (const int*)ei;
      s = p[e0 + i]; d = p[NE + e0 + i];
    }
    int b = d >> BSH;
    pay[i] = ((unsigned)s << BSH) | (unsigned)(d & (BNODES - 1));
    bk[i] = (unsigned short)b;
    atomicAdd(&hist[b], 1);
  }
  __syncthreads();
  int v = hist[t];
  lstart[t] = v;
  __syncthreads();
  for (int st = 1; st < 256; st <<= 1) {
    int xv = (t >= st) ? lstart[t - st] : 0;
    __syncthreads();
    lstart[t] += xv;
    __syncthreads();
  }
  int excl = lstart[t] - v;
  __syncthreads();
  lstart[t] = excl;
  cur[t] = excl;
  gbase[t] = (v > 0) ? atomicAdd(&bcnt[t], v) : 0;
  __syncthreads();
  for (int i = t; i < cnt; i += 256) {
    int b = bk[i];
    int pos = atomicAdd(&cur[b], 1);
    spay[pos] = pay[i];
    sbk[pos] = (unsigned short)b;
  }
  __syncthreads();
  for (int i = t; i < cnt; i += 256) {
    int b = sbk[i];
    int o = gbase[b] + (i - lstart[b]);
    if (o < BCAP) subbuf[(size_t)b * BCAP + o] = spay[i];
  }
}

// ---- bucket totals -> exclusive scan -> bucket_base ----------------------
__global__ void k_bucketsum(const int* __restrict__ bcnt, int* __restrict__ bucket_base,
                            int* __restrict__ row_start) {
  __shared__ int sh[256];
  int t = threadIdx.x;
  int tot = 0;
  if (t < NBUC) {
    int d0 = t << BSH;
    int nloc = min(BNODES, NN - d0);
    tot = nloc + min(bcnt[t], BCAP);
  }
  sh[t] = tot;
  __syncthreads();
  for (int s = 1; s < 256; s <<= 1) {
    int x = (t >= s) ? sh[t - s] : 0;
    __syncthreads();
    sh[t] += x;
    __syncthreads();
  }
  if (t < NBUC) bucket_base[t] = sh[t] - tot;
  if (t == NBUC - 1) row_start[NN] = sh[t];
}

// ---- pass B: per-bucket LDS hist -> scan -> row_start + placement --------
__global__ __launch_bounds__(256) void k_passB(const int* __restrict__ bcnt,
                       const unsigned int* __restrict__ subbuf,
                       const int* __restrict__ bucket_base,
                       int* __restrict__ row_start, int* __restrict__ csr) {
  __shared__ int hist[BNODES];
  __shared__ int ps[256];
  __shared__ int cur[BNODES];
  int b = blockIdx.x, t = threadIdx.x;
  int d0 = b << BSH;
  int nloc = min(BNODES, NN - d0);
  hist[t] = 0; hist[t + 256] = 0;
  __syncthreads();
  int cnt = min(bcnt[b], BCAP);
  const unsigned int* sb = subbuf + (size_t)b * BCAP;
  for (int i = t; i < cnt; i += 256)
    atomicAdd(&hist[sb[i] & (BNODES - 1)], 1);
  __syncthreads();
  int j0 = 2 * t, j1 = 2 * t + 1;
  int s0 = (j0 < nloc) ? hist[j0] + 1 : 0;
  int s1 = (j1 < nloc) ? hist[j1] + 1 : 0;
  int pairsum = s0 + s1;
  ps[t] = pairsum;
  __syncthreads();
  for (int s = 1; s < 256; s <<= 1) {
    int x = (t >= s) ? ps[t - s] : 0;
    __syncthreads();
    ps[t] += x;
    __syncthreads();
  }
  int excl = ps[t] - pairsum + bucket_base[b];
  if (j0 < nloc) {
    row_start[d0 + j0] = excl;
    csr[excl] = d0 + j0;
    cur[j0] = excl + 1;
  }
  if (j1 < nloc) {
    int rs = excl + s0;
    row_start[d0 + j1] = rs;
    csr[rs] = d0 + j1;
    cur[j1] = rs + 1;
  }
  __syncthreads();
  for (int i = t; i < cnt; i += 256) {
    unsigned u = sb[i];
    int pos = atomicAdd(&cur[u & (BNODES - 1)], 1);
    csr[pos] = (int)(u >> BSH);
  }
}

// ---- layer 1 linear: LDS-tiled GEMM; h1 stored bf16; logits fp32 ---------
#define XS1(node, k) xs[(node) * FIN + ((k) ^ ((node) & 31))]
__global__ void k_lin1(const float* __restrict__ x, const float* __restrict__ W,
                       const float* __restrict__ aw_s, const float* __restrict__ aw_d,
                       unsigned short* __restrict__ h, float* __restrict__ als,
                       float* __restrict__ ald) {
  __shared__ float ws[FIN * D1];
  __shared__ float xs[LNT * FIN];
  int t = threadIdx.x;
  int base = blockIdx.x * LNT;
  for (int i = t; i < FIN * D1; i += 256) ws[i] = W[i];
  for (int i = t; i < LNT * FIN; i += 256) {
    int node = i >> 7, k = i & 127;
    int gn = base + node;
    if (gn >= NN) gn = NN - 1;
    XS1(node, k) = x[(size_t)gn * FIN + k];
  }
  __syncthreads();
  int head = t & 7, ng = t >> 3;
  int n0l = ng * 2, n1l = n0l + 1;
  float acc0[8] = {0, 0, 0, 0, 0, 0, 0, 0};
  float acc1[8] = {0, 0, 0, 0, 0, 0, 0, 0};
  #pragma unroll 4
  for (int k = 0; k < FIN; ++k) {
    float x0 = XS1(n0l, k);
    float x1v = XS1(n1l, k);
    const float4* wr = (const float4*)&ws[k * D1 + head * 8];
    float4 wa = wr[0], wb = wr[1];
    acc0[0] = fmaf(x0, wa.x, acc0[0]); acc1[0] = fmaf(x1v, wa.x, acc1[0]);
    acc0[1] = fmaf(x0, wa.y, acc0[1]); acc1[1] = fmaf(x1v, wa.y, acc1[1]);
    acc0[2] = fmaf(x0, wa.z, acc0[2]); acc1[2] = fmaf(x1v, wa.z, acc1[2]);
    acc0[3] = fmaf(x0, wa.w, acc0[3]); acc1[3] = fmaf(x1v, wa.w, acc1[3]);
    acc0[4] = fmaf(x0, wb.x, acc0[4]); acc1[4] = fmaf(x1v, wb.x, acc1[4]);
    acc0[5] = fmaf(x0, wb.y, acc0[5]); acc1[5] = fmaf(x1v, wb.y, acc1[5]);
    acc0[6] = fmaf(x0, wb.z, acc0[6]); acc1[6] = fmaf(x1v, wb.z, acc1[6]);
    acc0[7] = fmaf(x0, wb.w, acc0[7]); acc1[7] = fmaf(x1v, wb.w, acc1[7]);
  }
  int n0 = base + n0l, n1 = base + n1l;
  float aws[8], awd[8];
  #pragma unroll
  for (int c = 0; c < 8; ++c) { aws[c] = aw_s[head * 8 + c]; awd[c] = aw_d[head * 8 + c]; }
  if (n0 < NN) {
    float s = 0.f, d = 0.f;
    #pragma unroll
    for (int c = 0; c < 8; ++c) {
      h[(size_t)n0 * D1 + head * 8 + c] = f2bf(acc0[c]);
      s = fmaf(acc0[c], aws[c], s);
      d = fmaf(acc0[c], awd[c], d);
    }
    als[n0 * H1N + head] = s;
    ald[n0 * H1N + head] = d;
  }
  if (n1 < NN) {
    float s = 0.f, d = 0.f;
    #pragma unroll
    for (int c = 0; c < 8; ++c) {
      h[(size_t)n1 * D1 + head * 8 + c] = f2bf(acc1[c]);
      s = fmaf(acc1[c], aws[c], s);
      d = fmaf(acc1[c], awd[c], d);
    }
    als[n1 * H1N + head] = s;
    ald[n1 * H1N + head] = d;
  }
}

// ---- layer 2 linear: LDS-tiled GEMM; h2 stored bf16; logits fp32 ---------
#define XS2(node, k) xs[(node) * D1 + ((k) ^ ((node) & 31))]
__global__ void k_lin2(const float* __restrict__ x, const float* __restrict__ W,
                       const float* __restrict__ aw_s, const float* __restrict__ aw_d,
                       unsigned short* __restrict__ h, float* __restrict__ als,
                       float* __restrict__ ald) {
  __shared__ float ws[D1 * D1];
  __shared__ float xs[LNT * D1];
  int t = threadIdx.x;
  int base = blockIdx.x * LNT;
  for (int i = t; i < D1 * D1; i += 256) {
    int k = i >> 6, c = i & 63;
    ws[i] = (c < NC) ? W[k * NC + c] : 0.f;
  }
  for (int i = t; i < LNT * D1; i += 256) {
    int node = i >> 6, k = i & 63;
    int gn = base + node;
    if (gn >= NN) gn = NN - 1;
    XS2(node, k) = x[(size_t)gn * D1 + k];
  }
  __syncthreads();
  int g = t & 7, ng = t >> 3;
  int n0l = ng * 2, n1l = n0l + 1;
  float acc0[8] = {0, 0, 0, 0, 0, 0, 0, 0};
  float acc1[8] = {0, 0, 0, 0, 0, 0, 0, 0};
  #pragma unroll 4
  for (int k = 0; k < D1; ++k) {
    float x0 = XS2(n0l, k);
    float x1v = XS2(n1l, k);
    const float4* wr = (const float4*)&ws[k * D1 + g * 8];
    float4 wa = wr[0], wb = wr[1];
    acc0[0] = fmaf(x0, wa.x, acc0[0]); acc1[0] = fmaf(x1v, wa.x, acc1[0]);
    acc0[1] = fmaf(x0, wa.y, acc0[1]); acc1[1] = fmaf(x1v, wa.y, acc1[1]);
    acc0[2] = fmaf(x0, wa.z, acc0[2]); acc1[2] = fmaf(x1v, wa.z, acc1[2]);
    acc0[3] = fmaf(x0, wa.w, acc0[3]); acc1[3] = fmaf(x1v, wa.w, acc1[3]);
    acc0[4] = fmaf(x0, wb.x, acc0[4]); acc1[4] = fmaf(x1v, wb.x, acc1[4]);
    acc0[5] = fmaf(x0, wb.y, acc0[5]); acc1[5] = fmaf(x1v, wb.y, acc1[5]);
    acc0[6] = fmaf(x0, wb.z, acc0[6]); acc1[6] = fmaf(x1v, wb.z, acc1[6]);
    acc0[7] = fmaf(x0, wb.w, acc0[7]); acc1[7] = fmaf(x1v, wb.w, acc1[7]);
  }
  int n0 = base + n0l, n1 = base + n1l;
  float aws[8], awd[8];
  #pragma unroll
  for (int c = 0; c < 8; ++c) {
    int col = g * 8 + c;
    aws[c] = (col < NC) ? aw_s[col] : 0.f;
    awd[c] = (col < NC) ? aw_d[col] : 0.f;
  }
  float s0 = 0.f, d0 = 0.f, s1 = 0.f, d1 = 0.f;
  #pragma unroll
  for (int c = 0; c < 8; ++c) {
    s0 = fmaf(acc0[c], aws[c], s0); d0 = fmaf(acc0[c], awd[c], d0);
    s1 = fmaf(acc1[c], aws[c], s1); d1 = fmaf(acc1[c], awd[c], d1);
  }
  s0 += __shfl_xor(s0, 1); d0 += __shfl_xor(d0, 1); s1 += __shfl_xor(s1, 1); d1 += __shfl_xor(d1, 1);
  s0 += __shfl_xor(s0, 2); d0 += __shfl_xor(d0, 2); s1 += __shfl_xor(s1, 2); d1 += __shfl_xor(d1, 2);
  s0 += __shfl_xor(s0, 4); d0 += __shfl_xor(d0, 4); s1 += __shfl_xor(s1, 4); d1 += __shfl_xor(d1, 4);
  if (n0 < NN && g < 5) {
    #pragma unroll
    for (int c = 0; c < 8; ++c) h[(size_t)n0 * NC + g * 8 + c] = f2bf(acc0[c]);
  }
  if (n1 < NN && g < 5) {
    #pragma unroll
    for (int c = 0; c < 8; ++c) h[(size_t)n1 * NC + g * 8 + c] = f2bf(acc1[c]);
  }
  if (g == 0) {
    if (n0 < NN) { als[n0] = s0; ald[n0] = d0; }
    if (n1 < NN) { als[n1] = s1; ald[n1] = d1; }
  }
}

// ---- layer 1 fused aggregate: bf16 gather rows (128B/row) -----------------
__global__ void k_node1(const int* __restrict__ row_start, const int* __restrict__ csr,
                        const unsigned short* __restrict__ h, const float* __restrict__ als,
                        const float* __restrict__ ald, const float* __restrict__ b,
                        float* __restrict__ x1) {
  __shared__ float pl[4][64 * 9];
  int wid = threadIdx.x >> 6, lane = threadIdx.x & 63;
  int n = blockIdx.x * 4 + wid;
  if (n >= NN) return;
  float* pw = pl[wid];
  int r0 = row_start[n], r1 = row_start[n + 1];
  int hd = lane >> 3;
  const float4* adp = (const float4*)(ald + (size_t)n * H1N);
  float4 ad0 = adp[0], ad1 = adp[1];
  float S = 0.f, acc0 = 0.f, acc1 = 0.f, acc2 = 0.f, acc3 = 0.f;
  for (int kb = r0; kb < r1; kb += 64) {
    int cnt = min(64, r1 - kb);
    if (lane < cnt) {
      int sk = csr[kb + lane];
      const float4* ap = (const float4*)(als + (size_t)sk * H1N);
      float4 a0 = ap[0], a1 = ap[1];
      pw[lane * 9 + 0] = __expf(leakyf(a0.x + ad0.x));
      pw[lane * 9 + 1] = __expf(leakyf(a0.y + ad0.y));
      pw[lane * 9 + 2] = __expf(leakyf(a0.z + ad0.z));
      pw[lane * 9 + 3] = __expf(leakyf(a0.w + ad0.w));
      pw[lane * 9 + 4] = __expf(leakyf(a1.x + ad1.x));
      pw[lane * 9 + 5] = __expf(leakyf(a1.y + ad1.y));
      pw[lane * 9 + 6] = __expf(leakyf(a1.z + ad1.z));
      pw[lane * 9 + 7] = __expf(leakyf(a1.w + ad1.w));
      pw[lane * 9 + 8] = __int_as_float(sk);
    }
    asm volatile("s_waitcnt lgkmcnt(0)" ::: "memory");   // wave-internal LDS RAW
    int j = 0;
    for (; j + 4 <= cnt; j += 4) {
      int s0 = __float_as_int(pw[(j + 0) * 9 + 8]);
      int s1 = __float_as_int(pw[(j + 1) * 9 + 8]);
      int s2 = __float_as_int(pw[(j + 2) * 9 + 8]);
      int s3 = __float_as_int(pw[(j + 3) * 9 + 8]);
      float p0 = pw[(j + 0) * 9 + hd], p1 = pw[(j + 1) * 9 + hd];
      float p2 = pw[(j + 2) * 9 + hd], p3 = pw[(j + 3) * 9 + hd];
      unsigned short u0 = h[(unsigned)s0 * D1 + lane];
      unsigned short u1 = h[(unsigned)s1 * D1 + lane];
      unsigned short u2 = h[(unsigned)s2 * D1 + lane];
      unsigned short u3 = h[(unsigned)s3 * D1 + lane];
      acc0 = fmaf(p0, bf2f(u0), acc0);
      acc1 = fmaf(p1, bf2f(u1), acc1);
      acc2 = fmaf(p2, bf2f(u2), acc2);
      acc3 = fmaf(p3, bf2f(u3), acc3);
      S += (p0 + p1) + (p2 + p3);
    }
    for (; j < cnt; ++j) {
      int s0 = __float_as_int(pw[j * 9 + 8]);
      float p0 = pw[j * 9 + hd];
      acc0 = fmaf(p0, bf2f(h[(unsigned)s0 * D1 + lane]), acc0);
      S += p0;
    }
  }
  float acc = (acc0 + acc1) + (acc2 + acc3);
  x1[(size_t)n * D1 + lane] = eluf(acc / (S + 1e-16f) + b[lane]);
}

// ---- layer 2 fused aggregate: bf16 gather rows (80B/row) ------------------
__global__ void k_node2(const int* __restrict__ row_start, const int* __restrict__ csr,
                        const unsigned short* __restrict__ h, const float* __restrict__ als,
                        const float* __restrict__ ald, const float* __restrict__ b,
                        float* __restrict__ out) {
  __shared__ float pl[4][64 * 3];
  int wid = threadIdx.x >> 6, lane = threadIdx.x & 63;
  int n = blockIdx.x * 4 + wid;
  if (n >= NN) return;
  float* pw = pl[wid];
  int r0 = row_start[n], r1 = row_start[n + 1];
  int cl = lane < NC ? lane : NC - 1;
  float aldn = ald[n];
  float S = 0.f, acc0 = 0.f, acc1 = 0.f, acc2 = 0.f, acc3 = 0.f;
  for (int kb = r0; kb < r1; kb += 64) {
    int cnt = min(64, r1 - kb);
    if (lane < cnt) {
      int sk = csr[kb + lane];
      pw[lane * 3 + 0] = __expf(leakyf(als[sk] + aldn));
      pw[lane * 3 + 1] = __int_as_float(sk);
    }
    asm volatile("s_waitcnt lgkmcnt(0)" ::: "memory");
    int j = 0;
    for (; j + 4 <= cnt; j += 4) {
      int s0 = __float_as_int(pw[(j + 0) * 3 + 1]);
      int s1 = __float_as_int(pw[(j + 1) * 3 + 1]);
      int s2 = __float_as_int(pw[(j + 2) * 3 + 1]);
      int s3 = __float_as_int(pw[(j + 3) * 3 + 1]);
      float p0 = pw[(j + 0) * 3], p1 = pw[(j + 1) * 3];
      float p2 = pw[(j + 2) * 3], p3 = pw[(j + 3) * 3];
      unsigned short u0 = h[(unsigned)s0 * NC + cl];
      unsigned short u1 = h[(unsigned)s1 * NC + cl];
      unsigned short u2 = h[(unsigned)s2 * NC + cl];
      unsigned short u3 = h[(unsigned)s3 * NC + cl];
      acc0 = fmaf(p0, bf2f(u0), acc0);
      acc1 = fmaf(p1, bf2f(u1), acc1);
      acc2 = fmaf(p2, bf2f(u2), acc2);
      acc3 = fmaf(p3, bf2f(u3), acc3);
      S += (p0 + p1) + (p2 + p3);
    }
    for (; j < cnt; ++j) {
      int s0 = __float_as_int(pw[j * 3 + 1]);
      float p0 = pw[j * 3];
      acc0 = fmaf(p0, bf2f(h[(unsigned)s0 * NC + cl]), acc0);
      S += p0;
    }
  }
  float acc = (acc0 + acc1) + (acc2 + acc3);
  if (lane < NC) out[(size_t)n * NC + lane] = eluf(acc / (S + 1e-16f) + b[lane]);
}

extern "C" void kernel_launch(void* const* d_in, const int* in_sizes, int n_in,
                              void* d_out, int out_size, void* d_ws, size_t ws_size,
                              hipStream_t stream) {
  const float* x    = (const float*)d_in[0];
  const void*  ei   = d_in[1];
  const float* W1   = (const float*)d_in[3];
  const float* as1w = (const float*)d_in[4];
  const float* ad1w = (const float*)d_in[5];
  const float* b1   = (const float*)d_in[6];
  const float* W2   = (const float*)d_in[7];
  const float* as2w = (const float*)d_in[8];
  const float* ad2w = (const float*)d_in[9];
  const float* b2   = (const float*)d_in[10];
  float* out = (float*)d_out;

  char* w = (char*)d_ws;
  size_t off = 0;
  auto carve = [&](size_t bytes) -> void* {
    void* r = w + off;
    off += (bytes + 255) & ~(size_t)255;
    return r;
  };
  int*            flag        = (int*)carve(256);
  int*            bcnt        = (int*)carve((size_t)NBUC * 4);
  int*            bucket_base = (int*)carve((size_t)NBUC * 4);
  unsigned int*   subbuf      = (unsigned int*)carve((size_t)NBUC * BCAP * 4);
  int*            row_start   = (int*)carve((size_t)(NN + 1) * 4);
  int*            csr         = (int*)carve((size_t)NETOT * 4);
  unsigned short* h1          = (unsigned short*)carve((size_t)NN * D1 * 2);  // bf16; reused as h2
  float*          als1        = (float*)carve((size_t)NN * H1N * 4);  // reused as als2
  float*          ald1        = (float*)carve((size_t)NN * H1N * 4);  // reused as ald2
  float*          x1          = (float*)carve((size_t)NN * D1 * 4);
  unsigned short* h2 = h1; float* als2 = als1; float* ald2 = ald1;

  const int LB = (NN + LNT - 1) / LNT;

  // CSR build: detect -> block-local sort+scatter -> bucket scan -> place
  k_detect<<<1, 64, 0, stream>>>((const long long*)ei, flag);
  hipMemsetAsync(bcnt, 0, (size_t)NBUC * 4, stream);
  k_passA<<<NBLKA, 256, 0, stream>>>(ei, flag, subbuf, bcnt);
  k_bucketsum<<<1, 256, 0, stream>>>(bcnt, bucket_base, row_start);
  k_passB<<<NBUC, 256, 0, stream>>>(bcnt, subbuf, bucket_base, row_start, csr);

  // layer 1
  k_lin1<<<LB, 256, 0, stream>>>(x, W1, as1w, ad1w, h1, als1, ald1);
  k_node1<<<NN / 4, 256, 0, stream>>>(row_start, csr, h1, als1, ald1, b1, x1);

  // layer 2
  k_lin2<<<LB, 256, 0, stream>>>(x1, W2, as2w, ad2w, h2, als2, ald2);
  k_node2<<<NN / 4, 256, 0, stream>>>(row_start, csr, h2, als2, ald2, b2, out);
}

// Round 9
// 239.092 us; speedup vs baseline: 2.2096x; 1.0181x over previous
//
#include <hip/hip_runtime.h>
#include <math.h>

#define NN 100000
#define NE 1600000
#define NETOT (NE + NN)
#define FIN 128
#define H1N 8
#define D1 64
#define NC 40
#define LNT 64                        // nodes per tile in lin kernels

#define BSH 9                         // 512 dst nodes per bucket
#define BNODES 512
#define NBUC ((NN + BNODES - 1) / BNODES)   // 196
#define EPB 4096                      // edges per passA block
#define NBLKA ((NE + EPB - 1) / EPB)  // 391
#define BCAP 9216                     // per-bucket edge capacity (mean 8192, +11 sigma)

__device__ __forceinline__ float leakyf(float x) { return x >= 0.0f ? x : 0.2f * x; }
__device__ __forceinline__ float eluf(float x)   { return x > 0.0f ? x : expm1f(x); }

// bf16 helpers
__device__ __forceinline__ unsigned short f2bf(float f) {
  unsigned u = __float_as_uint(f);
  u += 0x7fffu + ((u >> 16) & 1u);
  return (unsigned short)(u >> 16);
}
__device__ __forceinline__ float bflo(unsigned u) { return __uint_as_float(u << 16); }
__device__ __forceinline__ float bfhi(unsigned u) { return __uint_as_float(u & 0xffff0000u); }

// ---- edge_index dtype detection (int64 vs int32) ------------------------
__global__ void k_detect(const long long* __restrict__ ei, int* __restrict__ flag) {
  if (blockIdx.x == 0 && threadIdx.x == 0) {
    int is64 = 1;
    for (int i = 0; i < 16; ++i) {
      long long v = ei[i];
      if (v < 0 || v >= NN) is64 = 0;
    }
    *flag = is64;
  }
}

// ---- pass A: block-local LDS counting sort by bucket, coalesced write ----
__global__ __launch_bounds__(256) void k_passA(const void* __restrict__ ei,
                        const int* __restrict__ flag,
                        unsigned int* __restrict__ subbuf, int* __restrict__ bcnt) {
  __shared__ unsigned int   pay[EPB];
  __shared__ unsigned short bk[EPB];
  __shared__ unsigned int   spay[EPB];
  __shared__ unsigned short sbk[EPB];
  __shared__ int hist[256];
  __shared__ int lstart[256];
  __shared__ int cur[256];
  __shared__ int gbase[256];
  int t = threadIdx.x;
  int e0 = blockIdx.x * EPB;
  int cnt = min(EPB, NE - e0);
  hist[t] = 0;
  __syncthreads();
  bool f64 = (*flag) != 0;
  for (int i = t; i < cnt; i += 256) {
    int s, d;
    if (f64) {
      const long long* p = (const long long*)ei;
      s = (int)p[e0 + i]; d = (int)p[NE + e0 + i];
    } else {
      const int* p = (const int*)ei;
      s = p[e0 + i]; d = p[NE + e0 + i];
    }
    int b = d >> BSH;
    pay[i] = ((unsigned)s << BSH) | (unsigned)(d & (BNODES - 1));
    bk[i] = (unsigned short)b;
    atomicAdd(&hist[b], 1);
  }
  __syncthreads();
  int v = hist[t];
  lstart[t] = v;
  __syncthreads();
  for (int st = 1; st < 256; st <<= 1) {
    int xv = (t >= st) ? lstart[t - st] : 0;
    __syncthreads();
    lstart[t] += xv;
    __syncthreads();
  }
  int excl = lstart[t] - v;
  __syncthreads();
  lstart[t] = excl;
  cur[t] = excl;
  gbase[t] = (v > 0) ? atomicAdd(&bcnt[t], v) : 0;
  __syncthreads();
  for (int i = t; i < cnt; i += 256) {
    int b = bk[i];
    int pos = atomicAdd(&cur[b], 1);
    spay[pos] = pay[i];
    sbk[pos] = (unsigned short)b;
  }
  __syncthreads();
  for (int i = t; i < cnt; i += 256) {
    int b = sbk[i];
    int o = gbase[b] + (i - lstart[b]);
    if (o < BCAP) subbuf[(size_t)b * BCAP + o] = spay[i];
  }
}

// ---- bucket totals -> exclusive scan -> bucket_base ----------------------
__global__ void k_bucketsum(const int* __restrict__ bcnt, int* __restrict__ bucket_base,
                            int* __restrict__ row_start) {
  __shared__ int sh[256];
  int t = threadIdx.x;
  int tot = 0;
  if (t < NBUC) {
    int d0 = t << BSH;
    int nloc = min(BNODES, NN - d0);
    tot = nloc + min(bcnt[t], BCAP);
  }
  sh[t] = tot;
  __syncthreads();
  for (int s = 1; s < 256; s <<= 1) {
    int x = (t >= s) ? sh[t - s] : 0;
    __syncthreads();
    sh[t] += x;
    __syncthreads();
  }
  if (t < NBUC) bucket_base[t] = sh[t] - tot;
  if (t == NBUC - 1) row_start[NN] = sh[t];
}

// ---- pass B: per-bucket LDS hist -> scan -> row_start + placement --------
__global__ __launch_bounds__(256) void k_passB(const int* __restrict__ bcnt,
                       const unsigned int* __restrict__ subbuf,
                       const int* __restrict__ bucket_base,
                       int* __restrict__ row_start, int* __restrict__ csr) {
  __shared__ int hist[BNODES];
  __shared__ int ps[256];
  __shared__ int cur[BNODES];
  int b = blockIdx.x, t = threadIdx.x;
  int d0 = b << BSH;
  int nloc = min(BNODES, NN - d0);
  hist[t] = 0; hist[t + 256] = 0;
  __syncthreads();
  int cnt = min(bcnt[b], BCAP);
  const unsigned int* sb = subbuf + (size_t)b * BCAP;
  for (int i = t; i < cnt; i += 256)
    atomicAdd(&hist[sb[i] & (BNODES - 1)], 1);
  __syncthreads();
  int j0 = 2 * t, j1 = 2 * t + 1;
  int s0 = (j0 < nloc) ? hist[j0] + 1 : 0;
  int s1 = (j1 < nloc) ? hist[j1] + 1 : 0;
  int pairsum = s0 + s1;
  ps[t] = pairsum;
  __syncthreads();
  for (int s = 1; s < 256; s <<= 1) {
    int x = (t >= s) ? ps[t - s] : 0;
    __syncthreads();
    ps[t] += x;
    __syncthreads();
  }
  int excl = ps[t] - pairsum + bucket_base[b];
  if (j0 < nloc) {
    row_start[d0 + j0] = excl;
    csr[excl] = d0 + j0;
    cur[j0] = excl + 1;
  }
  if (j1 < nloc) {
    int rs = excl + s0;
    row_start[d0 + j1] = rs;
    csr[rs] = d0 + j1;
    cur[j1] = rs + 1;
  }
  __syncthreads();
  for (int i = t; i < cnt; i += 256) {
    unsigned u = sb[i];
    int pos = atomicAdd(&cur[u & (BNODES - 1)], 1);
    csr[pos] = (int)(u >> BSH);
  }
}

// ---- layer 1 linear: LDS-tiled GEMM; h1 stored bf16; logits fp32 ---------
#define XS1(node, k) xs[(node) * FIN + ((k) ^ ((node) & 31))]
__global__ void k_lin1(const float* __restrict__ x, const float* __restrict__ W,
                       const float* __restrict__ aw_s, const float* __restrict__ aw_d,
                       unsigned short* __restrict__ h, float* __restrict__ als,
                       float* __restrict__ ald) {
  __shared__ float ws[FIN * D1];
  __shared__ float xs[LNT * FIN];
  int t = threadIdx.x;
  int base = blockIdx.x * LNT;
  for (int i = t; i < FIN * D1; i += 256) ws[i] = W[i];
  for (int i = t; i < LNT * FIN; i += 256) {
    int node = i >> 7, k = i & 127;
    int gn = base + node;
    if (gn >= NN) gn = NN - 1;
    XS1(node, k) = x[(size_t)gn * FIN + k];
  }
  __syncthreads();
  int head = t & 7, ng = t >> 3;
  int n0l = ng * 2, n1l = n0l + 1;
  float acc0[8] = {0, 0, 0, 0, 0, 0, 0, 0};
  float acc1[8] = {0, 0, 0, 0, 0, 0, 0, 0};
  #pragma unroll 4
  for (int k = 0; k < FIN; ++k) {
    float x0 = XS1(n0l, k);
    float x1v = XS1(n1l, k);
    const float4* wr = (const float4*)&ws[k * D1 + head * 8];
    float4 wa = wr[0], wb = wr[1];
    acc0[0] = fmaf(x0, wa.x, acc0[0]); acc1[0] = fmaf(x1v, wa.x, acc1[0]);
    acc0[1] = fmaf(x0, wa.y, acc0[1]); acc1[1] = fmaf(x1v, wa.y, acc1[1]);
    acc0[2] = fmaf(x0, wa.z, acc0[2]); acc1[2] = fmaf(x1v, wa.z, acc1[2]);
    acc0[3] = fmaf(x0, wa.w, acc0[3]); acc1[3] = fmaf(x1v, wa.w, acc1[3]);
    acc0[4] = fmaf(x0, wb.x, acc0[4]); acc1[4] = fmaf(x1v, wb.x, acc1[4]);
    acc0[5] = fmaf(x0, wb.y, acc0[5]); acc1[5] = fmaf(x1v, wb.y, acc1[5]);
    acc0[6] = fmaf(x0, wb.z, acc0[6]); acc1[6] = fmaf(x1v, wb.z, acc1[6]);
    acc0[7] = fmaf(x0, wb.w, acc0[7]); acc1[7] = fmaf(x1v, wb.w, acc1[7]);
  }
  int n0 = base + n0l, n1 = base + n1l;
  float aws[8], awd[8];
  #pragma unroll
  for (int c = 0; c < 8; ++c) { aws[c] = aw_s[head * 8 + c]; awd[c] = aw_d[head * 8 + c]; }
  if (n0 < NN) {
    float s = 0.f, d = 0.f;
    #pragma unroll
    for (int c = 0; c < 8; ++c) {
      h[(size_t)n0 * D1 + head * 8 + c] = f2bf(acc0[c]);
      s = fmaf(acc0[c], aws[c], s);
      d = fmaf(acc0[c], awd[c], d);
    }
    als[n0 * H1N + head] = s;
    ald[n0 * H1N + head] = d;
  }
  if (n1 < NN) {
    float s = 0.f, d = 0.f;
    #pragma unroll
    for (int c = 0; c < 8; ++c) {
      h[(size_t)n1 * D1 + head * 8 + c] = f2bf(acc1[c]);
      s = fmaf(acc1[c], aws[c], s);
      d = fmaf(acc1[c], awd[c], d);
    }
    als[n1 * H1N + head] = s;
    ald[n1 * H1N + head] = d;
  }
}

// ---- layer 2 linear: LDS-tiled GEMM; h2 stored bf16; logits fp32 ---------
#define XS2(node, k) xs[(node) * D1 + ((k) ^ ((node) & 31))]
__global__ void k_lin2(const float* __restrict__ x, const float* __restrict__ W,
                       const float* __restrict__ aw_s, const float* __restrict__ aw_d,
                       unsigned short* __restrict__ h, float* __restrict__ als,
                       float* __restrict__ ald) {
  __shared__ float ws[D1 * D1];
  __shared__ float xs[LNT * D1];
  int t = threadIdx.x;
  int base = blockIdx.x * LNT;
  for (int i = t; i < D1 * D1; i += 256) {
    int k = i >> 6, c = i & 63;
    ws[i] = (c < NC) ? W[k * NC + c] : 0.f;
  }
  for (int i = t; i < LNT * D1; i += 256) {
    int node = i >> 6, k = i & 63;
    int gn = base + node;
    if (gn >= NN) gn = NN - 1;
    XS2(node, k) = x[(size_t)gn * D1 + k];
  }
  __syncthreads();
  int g = t & 7, ng = t >> 3;
  int n0l = ng * 2, n1l = n0l + 1;
  float acc0[8] = {0, 0, 0, 0, 0, 0, 0, 0};
  float acc1[8] = {0, 0, 0, 0, 0, 0, 0, 0};
  #pragma unroll 4
  for (int k = 0; k < D1; ++k) {
    float x0 = XS2(n0l, k);
    float x1v = XS2(n1l, k);
    const float4* wr = (const float4*)&ws[k * D1 + g * 8];
    float4 wa = wr[0], wb = wr[1];
    acc0[0] = fmaf(x0, wa.x, acc0[0]); acc1[0] = fmaf(x1v, wa.x, acc1[0]);
    acc0[1] = fmaf(x0, wa.y, acc0[1]); acc1[1] = fmaf(x1v, wa.y, acc1[1]);
    acc0[2] = fmaf(x0, wa.z, acc0[2]); acc1[2] = fmaf(x1v, wa.z, acc1[2]);
    acc0[3] = fmaf(x0, wa.w, acc0[3]); acc1[3] = fmaf(x1v, wa.w, acc1[3]);
    acc0[4] = fmaf(x0, wb.x, acc0[4]); acc1[4] = fmaf(x1v, wb.x, acc1[4]);
    acc0[5] = fmaf(x0, wb.y, acc0[5]); acc1[5] = fmaf(x1v, wb.y, acc1[5]);
    acc0[6] = fmaf(x0, wb.z, acc0[6]); acc1[6] = fmaf(x1v, wb.z, acc1[6]);
    acc0[7] = fmaf(x0, wb.w, acc0[7]); acc1[7] = fmaf(x1v, wb.w, acc1[7]);
  }
  int n0 = base + n0l, n1 = base + n1l;
  float aws[8], awd[8];
  #pragma unroll
  for (int c = 0; c < 8; ++c) {
    int col = g * 8 + c;
    aws[c] = (col < NC) ? aw_s[col] : 0.f;
    awd[c] = (col < NC) ? aw_d[col] : 0.f;
  }
  float s0 = 0.f, d0 = 0.f, s1 = 0.f, d1 = 0.f;
  #pragma unroll
  for (int c = 0; c < 8; ++c) {
    s0 = fmaf(acc0[c], aws[c], s0); d0 = fmaf(acc0[c], awd[c], d0);
    s1 = fmaf(acc1[c], aws[c], s1); d1 = fmaf(acc1[c], awd[c], d1);
  }
  s0 += __shfl_xor(s0, 1); d0 += __shfl_xor(d0, 1); s1 += __shfl_xor(s1, 1); d1 += __shfl_xor(d1, 1);
  s0 += __shfl_xor(s0, 2); d0 += __shfl_xor(d0, 2); s1 += __shfl_xor(s1, 2); d1 += __shfl_xor(d1, 2);
  s0 += __shfl_xor(s0, 4); d0 += __shfl_xor(d0, 4); s1 += __shfl_xor(s1, 4); d1 += __shfl_xor(d1, 4);
  if (n0 < NN && g < 5) {
    #pragma unroll
    for (int c = 0; c < 8; ++c) h[(size_t)n0 * NC + g * 8 + c] = f2bf(acc0[c]);
  }
  if (n1 < NN && g < 5) {
    #pragma unroll
    for (int c = 0; c < 8; ++c) h[(size_t)n1 * NC + g * 8 + c] = f2bf(acc1[c]);
  }
  if (g == 0) {
    if (n0 < NN) { als[n0] = s0; ald[n0] = d0; }
    if (n1 < NN) { als[n1] = s1; ald[n1] = d1; }
  }
}

// ---- layer 1 fused aggregate: dword-packed bf16, 2 edges per wave ---------
// lane = (pair = lane>>5, c2 = lane&31): lane owns channels {2c2, 2c2+1}
// (both in head c2>>2); pair p processes its own edge subset; one
// shfl_xor(32) folds the halves at the end.
__global__ void k_node1(const int* __restrict__ row_start, const int* __restrict__ csr,
                        const unsigned short* __restrict__ h, const float* __restrict__ als,
                        const float* __restrict__ ald, const float* __restrict__ b,
                        float* __restrict__ x1) {
  __shared__ float pl[4][64 * 9];
  int wid = threadIdx.x >> 6, lane = threadIdx.x & 63;
  int n = blockIdx.x * 4 + wid;
  if (n >= NN) return;
  float* pw = pl[wid];
  const unsigned int* h32 = (const unsigned int*)h;
  int r0 = row_start[n], r1 = row_start[n + 1];
  int pair = lane >> 5, c2 = lane & 31;
  int hd = c2 >> 2;
  int hd8 = lane >> 3;                       // staging-phase head (8 heads x 8 lanes)
  const float4* adp = (const float4*)(ald + (size_t)n * H1N);
  float4 ad0 = adp[0], ad1 = adp[1];
  float S = 0.f;
  float alo0 = 0.f, ahi0 = 0.f, alo1 = 0.f, ahi1 = 0.f;
  float alo2 = 0.f, ahi2 = 0.f, alo3 = 0.f, ahi3 = 0.f;
  for (int kb = r0; kb < r1; kb += 64) {
    int cnt = min(64, r1 - kb);
    if (lane < cnt) {
      int sk = csr[kb + lane];
      const float4* ap = (const float4*)(als + (size_t)sk * H1N);
      float4 a0 = ap[0], a1 = ap[1];
      pw[lane * 9 + 0] = __expf(leakyf(a0.x + ad0.x));
      pw[lane * 9 + 1] = __expf(leakyf(a0.y + ad0.y));
      pw[lane * 9 + 2] = __expf(leakyf(a0.z + ad0.z));
      pw[lane * 9 + 3] = __expf(leakyf(a0.w + ad0.w));
      pw[lane * 9 + 4] = __expf(leakyf(a1.x + ad1.x));
      pw[lane * 9 + 5] = __expf(leakyf(a1.y + ad1.y));
      pw[lane * 9 + 6] = __expf(leakyf(a1.z + ad1.z));
      pw[lane * 9 + 7] = __expf(leakyf(a1.w + ad1.w));
      pw[lane * 9 + 8] = __int_as_float(sk);
    }
    asm volatile("s_waitcnt lgkmcnt(0)" ::: "memory");   // wave-internal LDS RAW
    (void)hd8;
    int j = 0;
    for (; j + 8 <= cnt; j += 8) {
      int e = j + pair * 4;
      int s0 = __float_as_int(pw[(e + 0) * 9 + 8]);
      int s1 = __float_as_int(pw[(e + 1) * 9 + 8]);
      int s2 = __float_as_int(pw[(e + 2) * 9 + 8]);
      int s3 = __float_as_int(pw[(e + 3) * 9 + 8]);
      float p0 = pw[(e + 0) * 9 + hd], p1 = pw[(e + 1) * 9 + hd];
      float p2 = pw[(e + 2) * 9 + hd], p3 = pw[(e + 3) * 9 + hd];
      unsigned u0 = h32[(unsigned)s0 * 32 + c2];
      unsigned u1 = h32[(unsigned)s1 * 32 + c2];
      unsigned u2 = h32[(unsigned)s2 * 32 + c2];
      unsigned u3 = h32[(unsigned)s3 * 32 + c2];
      alo0 = fmaf(p0, bflo(u0), alo0); ahi0 = fmaf(p0, bfhi(u0), ahi0);
      alo1 = fmaf(p1, bflo(u1), alo1); ahi1 = fmaf(p1, bfhi(u1), ahi1);
      alo2 = fmaf(p2, bflo(u2), alo2); ahi2 = fmaf(p2, bfhi(u2), ahi2);
      alo3 = fmaf(p3, bflo(u3), alo3); ahi3 = fmaf(p3, bfhi(u3), ahi3);
      S += (p0 + p1) + (p2 + p3);
    }
    for (; j + 2 <= cnt; j += 2) {
      int e = j + pair;
      int s0 = __float_as_int(pw[e * 9 + 8]);
      float p0 = pw[e * 9 + hd];
      unsigned u0 = h32[(unsigned)s0 * 32 + c2];
      alo0 = fmaf(p0, bflo(u0), alo0); ahi0 = fmaf(p0, bfhi(u0), ahi0);
      S += p0;
    }
    if (j < cnt && pair == 0) {
      int s0 = __float_as_int(pw[j * 9 + 8]);
      float p0 = pw[j * 9 + hd];
      unsigned u0 = h32[(unsigned)s0 * 32 + c2];
      alo0 = fmaf(p0, bflo(u0), alo0); ahi0 = fmaf(p0, bfhi(u0), ahi0);
      S += p0;
    }
  }
  float alo = (alo0 + alo1) + (alo2 + alo3);
  float ahi = (ahi0 + ahi1) + (ahi2 + ahi3);
  alo += __shfl_xor(alo, 32);
  ahi += __shfl_xor(ahi, 32);
  S   += __shfl_xor(S, 32);
  if (pair == 0) {
    float inv = 1.0f / (S + 1e-16f);
    float2 o;
    o.x = eluf(alo * inv + b[2 * c2 + 0]);
    o.y = eluf(ahi * inv + b[2 * c2 + 1]);
    ((float2*)x1)[(size_t)n * 32 + c2] = o;
  }
}

// ---- layer 2 fused aggregate: dword-packed bf16, 2 edges per wave ---------
// c2 in 0..19 covers 40 channels; lanes with c2>=20 compute garbage that is
// never written (loads stay in-bounds of the h carve).
__global__ void k_node2(const int* __restrict__ row_start, const int* __restrict__ csr,
                        const unsigned short* __restrict__ h, const float* __restrict__ als,
                        const float* __restrict__ ald, const float* __restrict__ b,
                        float* __restrict__ out) {
  __shared__ float pl[4][64 * 3];
  int wid = threadIdx.x >> 6, lane = threadIdx.x & 63;
  int n = blockIdx.x * 4 + wid;
  if (n >= NN) return;
  float* pw = pl[wid];
  const unsigned int* h32 = (const unsigned int*)h;
  int r0 = row_start[n], r1 = row_start[n + 1];
  int pair = lane >> 5, c2 = lane & 31;
  float aldn = ald[n];
  float S = 0.f;
  float alo0 = 0.f, ahi0 = 0.f, alo1 = 0.f, ahi1 = 0.f;
  float alo2 = 0.f, ahi2 = 0.f, alo3 = 0.f, ahi3 = 0.f;
  for (int kb = r0; kb < r1; kb += 64) {
    int cnt = min(64, r1 - kb);
    if (lane < cnt) {
      int sk = csr[kb + lane];
      pw[lane * 3 + 0] = __expf(leakyf(als[sk] + aldn));
      pw[lane * 3 + 1] = __int_as_float(sk);
    }
    asm volatile("s_waitcnt lgkmcnt(0)" ::: "memory");
    int j = 0;
    for (; j + 8 <= cnt; j += 8) {
      int e = j + pair * 4;
      int s0 = __float_as_int(pw[(e + 0) * 3 + 1]);
      int s1 = __float_as_int(pw[(e + 1) * 3 + 1]);
      int s2 = __float_as_int(pw[(e + 2) * 3 + 1]);
      int s3 = __float_as_int(pw[(e + 3) * 3 + 1]);
      float p0 = pw[(e + 0) * 3], p1 = pw[(e + 1) * 3];
      float p2 = pw[(e + 2) * 3], p3 = pw[(e + 3) * 3];
      unsigned u0 = h32[(unsigned)s0 * 20 + c2 % 20];
      unsigned u1 = h32[(unsigned)s1 * 20 + c2 % 20];
      unsigned u2 = h32[(unsigned)s2 * 20 + c2 % 20];
      unsigned u3 = h32[(unsigned)s3 * 20 + c2 % 20];
      alo0 = fmaf(p0, bflo(u0), alo0); ahi0 = fmaf(p0, bfhi(u0), ahi0);
      alo1 = fmaf(p1, bflo(u1), alo1); ahi1 = fmaf(p1, bfhi(u1), ahi1);
      alo2 = fmaf(p2, bflo(u2), alo2); ahi2 = fmaf(p2, bfhi(u2), ahi2);
      alo3 = fmaf(p3, bflo(u3), alo3); ahi3 = fmaf(p3, bfhi(u3), ahi3);
      S += (p0 + p1) + (p2 + p3);
    }
    for (; j + 2 <= cnt; j += 2) {
      int e = j + pair;
      int s0 = __float_as_int(pw[e * 3 + 1]);
      float p0 = pw[e * 3];
      unsigned u0 = h32[(unsigned)s0 * 20 + c2 % 20];
      alo0 = fmaf(p0, bflo(u0), alo0); ahi0 = fmaf(p0, bfhi(u0), ahi0);
      S += p0;
    }
    if (j < cnt && pair == 0) {
      int s0 = __float_as_int(pw[j * 3 + 1]);
      float p0 = pw[j * 3];
      unsigned u0 = h32[(unsigned)s0 * 20 + c2 % 20];
      alo0 = fmaf(p0, bflo(u0), alo0); ahi0 = fmaf(p0, bfhi(u0), ahi0);
      S += p0;
    }
  }
  float alo = (alo0 + alo1) + (alo2 + alo3);
  float ahi = (ahi0 + ahi1) + (ahi2 + ahi3);
  alo += __shfl_xor(alo, 32);
  ahi += __shfl_xor(ahi, 32);
  S   += __shfl_xor(S, 32);
  if (pair == 0 && c2 < 20) {
    float inv = 1.0f / (S + 1e-16f);
    float2 o;
    o.x = eluf(alo * inv + b[2 * c2 + 0]);
    o.y = eluf(ahi * inv + b[2 * c2 + 1]);
    ((float2*)out)[(size_t)n * 20 + c2] = o;
  }
}

extern "C" void kernel_launch(void* const* d_in, const int* in_sizes, int n_in,
                              void* d_out, int out_size, void* d_ws, size_t ws_size,
                              hipStream_t stream) {
  const float* x    = (const float*)d_in[0];
  const void*  ei   = d_in[1];
  const float* W1   = (const float*)d_in[3];
  const float* as1w = (const float*)d_in[4];
  const float* ad1w = (const float*)d_in[5];
  const float* b1   = (const float*)d_in[6];
  const float* W2   = (const float*)d_in[7];
  const float* as2w = (const float*)d_in[8];
  const float* ad2w = (const float*)d_in[9];
  const float* b2   = (const float*)d_in[10];
  float* out = (float*)d_out;

  char* w = (char*)d_ws;
  size_t off = 0;
  auto carve = [&](size_t bytes) -> void* {
    void* r = w + off;
    off += (bytes + 255) & ~(size_t)255;
    return r;
  };
  int*            flag        = (int*)carve(256);
  int*            bcnt        = (int*)carve((size_t)NBUC * 4);
  int*            bucket_base = (int*)carve((size_t)NBUC * 4);
  unsigned int*   subbuf      = (unsigned int*)carve((size_t)NBUC * BCAP * 4);
  int*            row_start   = (int*)carve((size_t)(NN + 1) * 4);
  int*            csr         = (int*)carve((size_t)NETOT * 4);
  unsigned short* h1          = (unsigned short*)carve((size_t)NN * D1 * 2);  // bf16; reused as h2
  float*          als1        = (float*)carve((size_t)NN * H1N * 4);  // reused as als2
  float*          ald1        = (float*)carve((size_t)NN * H1N * 4);  // reused as ald2
  float*          x1          = (float*)carve((size_t)NN * D1 * 4);
  unsigned short* h2 = h1; float* als2 = als1; float* ald2 = ald1;

  const int LB = (NN + LNT - 1) / LNT;

  // CSR build: detect -> block-local sort+scatter -> bucket scan -> place
  k_detect<<<1, 64, 0, stream>>>((const long long*)ei, flag);
  hipMemsetAsync(bcnt, 0, (size_t)NBUC * 4, stream);
  k_passA<<<NBLKA, 256, 0, stream>>>(ei, flag, subbuf, bcnt);
  k_bucketsum<<<1, 256, 0, stream>>>(bcnt, bucket_base, row_start);
  k_passB<<<NBUC, 256, 0, stream>>>(bcnt, subbuf, bucket_base, row_start, csr);

  // layer 1
  k_lin1<<<LB, 256, 0, stream>>>(x, W1, as1w, ad1w, h1, als1, ald1);
  k_node1<<<NN / 4, 256, 0, stream>>>(row_start, csr, h1, als1, ald1, b1, x1);

  // layer 2
  k_lin2<<<LB, 256, 0, stream>>>(x1, W2, as2w, ad2w, h2, als2, ald2);
  k_node2<<<NN / 4, 256, 0, stream>>>(row_start, csr, h2, als2, ald2, b2, out);
}

// Round 11
// 217.836 us; speedup vs baseline: 2.4252x; 1.0976x over previous
//
#include <hip/hip_runtime.h>
#include <math.h>

#define NN 100000
#define NE 1600000
#define NETOT (NE + NN)
#define FIN 128
#define H1N 8
#define D1 64
#define NC 40
#define LNT 64                        // nodes per tile in lin kernels
#define LOG2E 1.44269504088896f

#define BSH 9                         // 512 dst nodes per bucket
#define BNODES 512
#define NBUC ((NN + BNODES - 1) / BNODES)   // 196
#define EPB 4096                      // edges per passA block
#define NBLKA ((NE + EPB - 1) / EPB)  // 391
#define BCAP 9216                     // per-bucket edge capacity (mean 8192, +11 sigma)

__device__ __forceinline__ float leakyf(float x) { return x >= 0.0f ? x : 0.2f * x; }
__device__ __forceinline__ float eluf(float x)   { return x > 0.0f ? x : expm1f(x); }
__device__ __forceinline__ float exp2fast(float x) { return __builtin_amdgcn_exp2f(x); }

// bf16 helpers
__device__ __forceinline__ unsigned short f2bf(float f) {
  unsigned u = __float_as_uint(f);
  u += 0x7fffu + ((u >> 16) & 1u);
  return (unsigned short)(u >> 16);
}
__device__ __forceinline__ float bflo(unsigned u) { return __uint_as_float(u << 16); }
__device__ __forceinline__ float bfhi(unsigned u) { return __uint_as_float(u & 0xffff0000u); }

// ---- edge_index dtype detection (int64 vs int32) ------------------------
__global__ void k_detect(const long long* __restrict__ ei, int* __restrict__ flag) {
  if (blockIdx.x == 0 && threadIdx.x == 0) {
    int is64 = 1;
    for (int i = 0; i < 16; ++i) {
      long long v = ei[i];
      if (v < 0 || v >= NN) is64 = 0;
    }
    *flag = is64;
  }
}

// ---- pass A: block-local LDS counting sort by bucket, coalesced write ----
__global__ __launch_bounds__(256) void k_passA(const void* __restrict__ ei,
                        const int* __restrict__ flag,
                        unsigned int* __restrict__ subbuf, int* __restrict__ bcnt) {
  __shared__ unsigned int   pay[EPB];
  __shared__ unsigned short bk[EPB];
  __shared__ unsigned int   spay[EPB];
  __shared__ unsigned short sbk[EPB];
  __shared__ int hist[256];
  __shared__ int lstart[256];
  __shared__ int cur[256];
  __shared__ int gbase[256];
  int t = threadIdx.x;
  int e0 = blockIdx.x * EPB;
  int cnt = min(EPB, NE - e0);
  hist[t] = 0;
  __syncthreads();
  bool f64 = (*flag) != 0;
  for (int i = t; i < cnt; i += 256) {
    int s, d;
    if (f64) {
      const long long* p = (const long long*)ei;
      s = (int)p[e0 + i]; d = (int)p[NE + e0 + i];
    } else {
      const int* p = (const int*)ei;
      s = p[e0 + i]; d = p[NE + e0 + i];
    }
    int b = d >> BSH;
    pay[i] = ((unsigned)s << BSH) | (unsigned)(d & (BNODES - 1));
    bk[i] = (unsigned short)b;
    atomicAdd(&hist[b], 1);
  }
  __syncthreads();
  int v = hist[t];
  lstart[t] = v;
  __syncthreads();
  for (int st = 1; st < 256; st <<= 1) {
    int xv = (t >= st) ? lstart[t - st] : 0;
    __syncthreads();
    lstart[t] += xv;
    __syncthreads();
  }
  int excl = lstart[t] - v;
  __syncthreads();
  lstart[t] = excl;
  cur[t] = excl;
  gbase[t] = (v > 0) ? atomicAdd(&bcnt[t], v) : 0;
  __syncthreads();
  for (int i = t; i < cnt; i += 256) {
    int b = bk[i];
    int pos = atomicAdd(&cur[b], 1);
    spay[pos] = pay[i];
    sbk[pos] = (unsigned short)b;
  }
  __syncthreads();
  for (int i = t; i < cnt; i += 256) {
    int b = sbk[i];
    int o = gbase[b] + (i - lstart[b]);
    if (o < BCAP) subbuf[(size_t)b * BCAP + o] = spay[i];
  }
}

// ---- bucket totals -> exclusive scan -> bucket_base ----------------------
__global__ void k_bucketsum(const int* __restrict__ bcnt, int* __restrict__ bucket_base,
                            int* __restrict__ row_start) {
  __shared__ int sh[256];
  int t = threadIdx.x;
  int tot = 0;
  if (t < NBUC) {
    int d0 = t << BSH;
    int nloc = min(BNODES, NN - d0);
    tot = nloc + min(bcnt[t], BCAP);
  }
  sh[t] = tot;
  __syncthreads();
  for (int s = 1; s < 256; s <<= 1) {
    int x = (t >= s) ? sh[t - s] : 0;
    __syncthreads();
    sh[t] += x;
    __syncthreads();
  }
  if (t < NBUC) bucket_base[t] = sh[t] - tot;
  if (t == NBUC - 1) row_start[NN] = sh[t];
}

// ---- pass B: per-bucket LDS hist -> scan -> row_start + placement --------
__global__ __launch_bounds__(256) void k_passB(const int* __restrict__ bcnt,
                       const unsigned int* __restrict__ subbuf,
                       const int* __restrict__ bucket_base,
                       int* __restrict__ row_start, int* __restrict__ csr) {
  __shared__ int hist[BNODES];
  __shared__ int ps[256];
  __shared__ int cur[BNODES];
  int b = blockIdx.x, t = threadIdx.x;
  int d0 = b << BSH;
  int nloc = min(BNODES, NN - d0);
  hist[t] = 0; hist[t + 256] = 0;
  __syncthreads();
  int cnt = min(bcnt[b], BCAP);
  const unsigned int* sb = subbuf + (size_t)b * BCAP;
  for (int i = t; i < cnt; i += 256)
    atomicAdd(&hist[sb[i] & (BNODES - 1)], 1);
  __syncthreads();
  int j0 = 2 * t, j1 = 2 * t + 1;
  int s0 = (j0 < nloc) ? hist[j0] + 1 : 0;
  int s1 = (j1 < nloc) ? hist[j1] + 1 : 0;
  int pairsum = s0 + s1;
  ps[t] = pairsum;
  __syncthreads();
  for (int s = 1; s < 256; s <<= 1) {
    int x = (t >= s) ? ps[t - s] : 0;
    __syncthreads();
    ps[t] += x;
    __syncthreads();
  }
  int excl = ps[t] - pairsum + bucket_base[b];
  if (j0 < nloc) {
    row_start[d0 + j0] = excl;
    csr[excl] = d0 + j0;
    cur[j0] = excl + 1;
  }
  if (j1 < nloc) {
    int rs = excl + s0;
    row_start[d0 + j1] = rs;
    csr[rs] = d0 + j1;
    cur[j1] = rs + 1;
  }
  __syncthreads();
  for (int i = t; i < cnt; i += 256) {
    unsigned u = sb[i];
    int pos = atomicAdd(&cur[u & (BNODES - 1)], 1);
    csr[pos] = (int)(u >> BSH);
  }
}

// ---- layer 1 linear: LDS-tiled GEMM; h1 bf16; logits fp32 (pre-scaled ----
// by log2e so the node kernels can use exp2 directly).
#define XS1(node, k) xs[(node) * FIN + ((k) ^ ((node) & 31))]
__global__ void k_lin1(const float* __restrict__ x, const float* __restrict__ W,
                       const float* __restrict__ aw_s, const float* __restrict__ aw_d,
                       unsigned short* __restrict__ h, float* __restrict__ als,
                       float* __restrict__ ald) {
  __shared__ float ws[FIN * D1];
  __shared__ float xs[LNT * FIN];
  int t = threadIdx.x;
  int base = blockIdx.x * LNT;
  for (int i = t; i < FIN * D1; i += 256) ws[i] = W[i];
  for (int i = t; i < LNT * FIN; i += 256) {
    int node = i >> 7, k = i & 127;
    int gn = base + node;
    if (gn >= NN) gn = NN - 1;
    XS1(node, k) = x[(size_t)gn * FIN + k];
  }
  __syncthreads();
  int head = t & 7, ng = t >> 3;
  int n0l = ng * 2, n1l = n0l + 1;
  float acc0[8] = {0, 0, 0, 0, 0, 0, 0, 0};
  float acc1[8] = {0, 0, 0, 0, 0, 0, 0, 0};
  #pragma unroll 4
  for (int k = 0; k < FIN; ++k) {
    float x0 = XS1(n0l, k);
    float x1v = XS1(n1l, k);
    const float4* wr = (const float4*)&ws[k * D1 + head * 8];
    float4 wa = wr[0], wb = wr[1];
    acc0[0] = fmaf(x0, wa.x, acc0[0]); acc1[0] = fmaf(x1v, wa.x, acc1[0]);
    acc0[1] = fmaf(x0, wa.y, acc0[1]); acc1[1] = fmaf(x1v, wa.y, acc1[1]);
    acc0[2] = fmaf(x0, wa.z, acc0[2]); acc1[2] = fmaf(x1v, wa.z, acc1[2]);
    acc0[3] = fmaf(x0, wa.w, acc0[3]); acc1[3] = fmaf(x1v, wa.w, acc1[3]);
    acc0[4] = fmaf(x0, wb.x, acc0[4]); acc1[4] = fmaf(x1v, wb.x, acc1[4]);
    acc0[5] = fmaf(x0, wb.y, acc0[5]); acc1[5] = fmaf(x1v, wb.y, acc1[5]);
    acc0[6] = fmaf(x0, wb.z, acc0[6]); acc1[6] = fmaf(x1v, wb.z, acc1[6]);
    acc0[7] = fmaf(x0, wb.w, acc0[7]); acc1[7] = fmaf(x1v, wb.w, acc1[7]);
  }
  int n0 = base + n0l, n1 = base + n1l;
  float aws[8], awd[8];
  #pragma unroll
  for (int c = 0; c < 8; ++c) { aws[c] = aw_s[head * 8 + c]; awd[c] = aw_d[head * 8 + c]; }
  if (n0 < NN) {
    float s = 0.f, d = 0.f;
    #pragma unroll
    for (int c = 0; c < 8; ++c) {
      h[(size_t)n0 * D1 + head * 8 + c] = f2bf(acc0[c]);
      s = fmaf(acc0[c], aws[c], s);
      d = fmaf(acc0[c], awd[c], d);
    }
    als[n0 * H1N + head] = s * LOG2E;
    ald[n0 * H1N + head] = d * LOG2E;
  }
  if (n1 < NN) {
    float s = 0.f, d = 0.f;
    #pragma unroll
    for (int c = 0; c < 8; ++c) {
      h[(size_t)n1 * D1 + head * 8 + c] = f2bf(acc1[c]);
      s = fmaf(acc1[c], aws[c], s);
      d = fmaf(acc1[c], awd[c], d);
    }
    als[n1 * H1N + head] = s * LOG2E;
    ald[n1 * H1N + head] = d * LOG2E;
  }
}

// ---- layer 2 linear: reads packed-bf16 x1; h2 bf16; logits pre-scaled ----
#define XS2(node, k) xs[(node) * D1 + ((k) ^ ((node) & 31))]
__global__ void k_lin2(const unsigned int* __restrict__ x1bf, const float* __restrict__ W,
                       const float* __restrict__ aw_s, const float* __restrict__ aw_d,
                       unsigned short* __restrict__ h, float* __restrict__ als,
                       float* __restrict__ ald) {
  __shared__ float ws[D1 * D1];
  __shared__ float xs[LNT * D1];
  int t = threadIdx.x;
  int base = blockIdx.x * LNT;
  for (int i = t; i < D1 * D1; i += 256) {
    int k = i >> 6, c = i & 63;
    ws[i] = (c < NC) ? W[k * NC + c] : 0.f;
  }
  for (int i = t; i < LNT * 32; i += 256) {
    int node = i >> 5, kd = i & 31;
    int gn = base + node;
    if (gn >= NN) gn = NN - 1;
    unsigned u = x1bf[(size_t)gn * 32 + kd];
    XS2(node, 2 * kd)     = bflo(u);
    XS2(node, 2 * kd + 1) = bfhi(u);
  }
  __syncthreads();
  int g = t & 7, ng = t >> 3;
  int n0l = ng * 2, n1l = n0l + 1;
  float acc0[8] = {0, 0, 0, 0, 0, 0, 0, 0};
  float acc1[8] = {0, 0, 0, 0, 0, 0, 0, 0};
  #pragma unroll 4
  for (int k = 0; k < D1; ++k) {
    float x0 = XS2(n0l, k);
    float x1v = XS2(n1l, k);
    const float4* wr = (const float4*)&ws[k * D1 + g * 8];
    float4 wa = wr[0], wb = wr[1];
    acc0[0] = fmaf(x0, wa.x, acc0[0]); acc1[0] = fmaf(x1v, wa.x, acc1[0]);
    acc0[1] = fmaf(x0, wa.y, acc0[1]); acc1[1] = fmaf(x1v, wa.y, acc1[1]);
    acc0[2] = fmaf(x0, wa.z, acc0[2]); acc1[2] = fmaf(x1v, wa.z, acc1[2]);
    acc0[3] = fmaf(x0, wa.w, acc0[3]); acc1[3] = fmaf(x1v, wa.w, acc1[3]);
    acc0[4] = fmaf(x0, wb.x, acc0[4]); acc1[4] = fmaf(x1v, wb.x, acc1[4]);
    acc0[5] = fmaf(x0, wb.y, acc0[5]); acc1[5] = fmaf(x1v, wb.y, acc1[5]);
    acc0[6] = fmaf(x0, wb.z, acc0[6]); acc1[6] = fmaf(x1v, wb.z, acc1[6]);
    acc0[7] = fmaf(x0, wb.w, acc0[7]); acc1[7] = fmaf(x1v, wb.w, acc1[7]);
  }
  int n0 = base + n0l, n1 = base + n1l;
  float aws[8], awd[8];
  #pragma unroll
  for (int c = 0; c < 8; ++c) {
    int col = g * 8 + c;
    aws[c] = (col < NC) ? aw_s[col] : 0.f;
    awd[c] = (col < NC) ? aw_d[col] : 0.f;
  }
  float s0 = 0.f, d0 = 0.f, s1 = 0.f, d1 = 0.f;
  #pragma unroll
  for (int c = 0; c < 8; ++c) {
    s0 = fmaf(acc0[c], aws[c], s0); d0 = fmaf(acc0[c], awd[c], d0);
    s1 = fmaf(acc1[c], aws[c], s1); d1 = fmaf(acc1[c], awd[c], d1);
  }
  s0 += __shfl_xor(s0, 1); d0 += __shfl_xor(d0, 1); s1 += __shfl_xor(s1, 1); d1 += __shfl_xor(d1, 1);
  s0 += __shfl_xor(s0, 2); d0 += __shfl_xor(d0, 2); s1 += __shfl_xor(s1, 2); d1 += __shfl_xor(d1, 2);
  s0 += __shfl_xor(s0, 4); d0 += __shfl_xor(d0, 4); s1 += __shfl_xor(s1, 4); d1 += __shfl_xor(d1, 4);
  if (n0 < NN && g < 5) {
    #pragma unroll
    for (int c = 0; c < 8; ++c) h[(size_t)n0 * NC + g * 8 + c] = f2bf(acc0[c]);
  }
  if (n1 < NN && g < 5) {
    #pragma unroll
    for (int c = 0; c < 8; ++c) h[(size_t)n1 * NC + g * 8 + c] = f2bf(acc1[c]);
  }
  if (g == 0) {
    if (n0 < NN) { als[n0] = s0 * LOG2E; ald[n0] = d0 * LOG2E; }
    if (n1 < NN) { als[n1] = s1 * LOG2E; ald[n1] = d1 * LOG2E; }
  }
}

// ---- layer 1 aggregate: 2 nodes/wave, independent 32-lane halves ---------
// Each half owns one node: lane c2 owns channels {2c2,2c2+1} (head c2>>2).
// All lanes of a half accumulate the full S -> no cross-lane reduction.
// Output x1 packed bf16 (2 ch/dword).
__global__ void k_node1(const int* __restrict__ row_start, const int* __restrict__ csr,
                        const unsigned short* __restrict__ h, const float* __restrict__ als,
                        const float* __restrict__ ald, const float* __restrict__ b,
                        unsigned int* __restrict__ x1bf) {
  __shared__ float pl[4][2][32 * 9];
  int wid = threadIdx.x >> 6, half = (threadIdx.x >> 5) & 1, c2 = threadIdx.x & 31;
  int n = blockIdx.x * 8 + wid * 2 + half;          // NN % 8 == 0
  float* pw = pl[wid][half];
  const unsigned int* h32 = (const unsigned int*)h;
  int r0 = row_start[n], r1 = row_start[n + 1];
  int hd = c2 >> 2;
  const float4* adp = (const float4*)(ald + (size_t)n * H1N);
  float4 ad0 = adp[0], ad1 = adp[1];
  float S = 0.f;
  float alo0 = 0.f, ahi0 = 0.f, alo1 = 0.f, ahi1 = 0.f;
  float alo2 = 0.f, ahi2 = 0.f, alo3 = 0.f, ahi3 = 0.f;
  for (int kb = r0; kb < r1; kb += 32) {
    int cnt = min(32, r1 - kb);
    if (c2 < cnt) {
      int sk = csr[kb + c2];
      const float4* ap = (const float4*)(als + (size_t)sk * H1N);
      float4 a0 = ap[0], a1 = ap[1];
      pw[c2 * 9 + 0] = exp2fast(leakyf(a0.x + ad0.x));
      pw[c2 * 9 + 1] = exp2fast(leakyf(a0.y + ad0.y));
      pw[c2 * 9 + 2] = exp2fast(leakyf(a0.z + ad0.z));
      pw[c2 * 9 + 3] = exp2fast(leakyf(a0.w + ad0.w));
      pw[c2 * 9 + 4] = exp2fast(leakyf(a1.x + ad1.x));
      pw[c2 * 9 + 5] = exp2fast(leakyf(a1.y + ad1.y));
      pw[c2 * 9 + 6] = exp2fast(leakyf(a1.z + ad1.z));
      pw[c2 * 9 + 7] = exp2fast(leakyf(a1.w + ad1.w));
      pw[c2 * 9 + 8] = __int_as_float(sk);
    }
    asm volatile("s_waitcnt lgkmcnt(0)" ::: "memory");   // wave-internal LDS RAW
    int j = 0;
    for (; j + 4 <= cnt; j += 4) {
      int s0 = __float_as_int(pw[(j + 0) * 9 + 8]);
      int s1 = __float_as_int(pw[(j + 1) * 9 + 8]);
      int s2 = __float_as_int(pw[(j + 2) * 9 + 8]);
      int s3 = __float_as_int(pw[(j + 3) * 9 + 8]);
      float p0 = pw[(j + 0) * 9 + hd], p1 = pw[(j + 1) * 9 + hd];
      float p2 = pw[(j + 2) * 9 + hd], p3 = pw[(j + 3) * 9 + hd];
      unsigned u0 = h32[(unsigned)s0 * 32 + c2];
      unsigned u1 = h32[(unsigned)s1 * 32 + c2];
      unsigned u2 = h32[(unsigned)s2 * 32 + c2];
      unsigned u3 = h32[(unsigned)s3 * 32 + c2];
      alo0 = fmaf(p0, bflo(u0), alo0); ahi0 = fmaf(p0, bfhi(u0), ahi0);
      alo1 = fmaf(p1, bflo(u1), alo1); ahi1 = fmaf(p1, bfhi(u1), ahi1);
      alo2 = fmaf(p2, bflo(u2), alo2); ahi2 = fmaf(p2, bfhi(u2), ahi2);
      alo3 = fmaf(p3, bflo(u3), alo3); ahi3 = fmaf(p3, bfhi(u3), ahi3);
      S += (p0 + p1) + (p2 + p3);
    }
    for (; j < cnt; ++j) {
      int s0 = __float_as_int(pw[j * 9 + 8]);
      float p0 = pw[j * 9 + hd];
      unsigned u0 = h32[(unsigned)s0 * 32 + c2];
      alo0 = fmaf(p0, bflo(u0), alo0); ahi0 = fmaf(p0, bfhi(u0), ahi0);
      S += p0;
    }
  }
  float alo = (alo0 + alo1) + (alo2 + alo3);
  float ahi = (ahi0 + ahi1) + (ahi2 + ahi3);
  float inv = 1.0f / (S + 1e-16f);
  float ox = eluf(alo * inv + b[2 * c2 + 0]);
  float oy = eluf(ahi * inv + b[2 * c2 + 1]);
  x1bf[(size_t)n * 32 + c2] = (unsigned)f2bf(ox) | ((unsigned)f2bf(oy) << 16);
}

// ---- layer 2 aggregate: 2 nodes/wave halves; fp32 output -----------------
__global__ void k_node2(const int* __restrict__ row_start, const int* __restrict__ csr,
                        const unsigned short* __restrict__ h, const float* __restrict__ als,
                        const float* __restrict__ ald, const float* __restrict__ b,
                        float* __restrict__ out) {
  __shared__ float pl[4][2][32 * 3];
  int wid = threadIdx.x >> 6, half = (threadIdx.x >> 5) & 1, c2 = threadIdx.x & 31;
  int n = blockIdx.x * 8 + wid * 2 + half;
  float* pw = pl[wid][half];
  const unsigned int* h32 = (const unsigned int*)h;
  int r0 = row_start[n], r1 = row_start[n + 1];
  int cl = c2 < 20 ? c2 : 19;
  float aldn = ald[n];
  float S = 0.f;
  float alo0 = 0.f, ahi0 = 0.f, alo1 = 0.f, ahi1 = 0.f;
  float alo2 = 0.f, ahi2 = 0.f, alo3 = 0.f, ahi3 = 0.f;
  for (int kb = r0; kb < r1; kb += 32) {
    int cnt = min(32, r1 - kb);
    if (c2 < cnt) {
      int sk = csr[kb + c2];
      pw[c2 * 3 + 0] = exp2fast(leakyf(als[sk] + aldn));
      pw[c2 * 3 + 1] = __int_as_float(sk);
    }
    asm volatile("s_waitcnt lgkmcnt(0)" ::: "memory");
    int j = 0;
    for (; j + 4 <= cnt; j += 4) {
      int s0 = __float_as_int(pw[(j + 0) * 3 + 1]);
      int s1 = __float_as_int(pw[(j + 1) * 3 + 1]);
      int s2 = __float_as_int(pw[(j + 2) * 3 + 1]);
      int s3 = __float_as_int(pw[(j + 3) * 3 + 1]);
      float p0 = pw[(j + 0) * 3], p1 = pw[(j + 1) * 3];
      float p2 = pw[(j + 2) * 3], p3 = pw[(j + 3) * 3];
      unsigned u0 = h32[(unsigned)s0 * 20 + cl];
      unsigned u1 = h32[(unsigned)s1 * 20 + cl];
      unsigned u2 = h32[(unsigned)s2 * 20 + cl];
      unsigned u3 = h32[(unsigned)s3 * 20 + cl];
      alo0 = fmaf(p0, bflo(u0), alo0); ahi0 = fmaf(p0, bfhi(u0), ahi0);
      alo1 = fmaf(p1, bflo(u1), alo1); ahi1 = fmaf(p1, bfhi(u1), ahi1);
      alo2 = fmaf(p2, bflo(u2), alo2); ahi2 = fmaf(p2, bfhi(u2), ahi2);
      alo3 = fmaf(p3, bflo(u3), alo3); ahi3 = fmaf(p3, bfhi(u3), ahi3);
      S += (p0 + p1) + (p2 + p3);
    }
    for (; j < cnt; ++j) {
      int s0 = __float_as_int(pw[j * 3 + 1]);
      float p0 = pw[j * 3];
      unsigned u0 = h32[(unsigned)s0 * 20 + cl];
      alo0 = fmaf(p0, bflo(u0), alo0); ahi0 = fmaf(p0, bfhi(u0), ahi0);
      S += p0;
    }
  }
  float alo = (alo0 + alo1) + (alo2 + alo3);
  float ahi = (ahi0 + ahi1) + (ahi2 + ahi3);
  if (c2 < 20) {
    float inv = 1.0f / (S + 1e-16f);
    float2 o;
    o.x = eluf(alo * inv + b[2 * c2 + 0]);
    o.y = eluf(ahi * inv + b[2 * c2 + 1]);
    ((float2*)out)[(size_t)n * 20 + c2] = o;
  }
}

extern "C" void kernel_launch(void* const* d_in, const int* in_sizes, int n_in,
                              void* d_out, int out_size, void* d_ws, size_t ws_size,
                              hipStream_t stream) {
  const float* x    = (const float*)d_in[0];
  const void*  ei   = d_in[1];
  const float* W1   = (const float*)d_in[3];
  const float* as1w = (const float*)d_in[4];
  const float* ad1w = (const float*)d_in[5];
  const float* b1   = (const float*)d_in[6];
  const float* W2   = (const float*)d_in[7];
  const float* as2w = (const float*)d_in[8];
  const float* ad2w = (const float*)d_in[9];
  const float* b2   = (const float*)d_in[10];
  float* out = (float*)d_out;

  char* w = (char*)d_ws;
  size_t off = 0;
  auto carve = [&](size_t bytes) -> void* {
    void* r = w + off;
    off += (bytes + 255) & ~(size_t)255;
    return r;
  };
  int*            flag        = (int*)carve(256);
  int*            bcnt        = (int*)carve((size_t)NBUC * 4);
  int*            bucket_base = (int*)carve((size_t)NBUC * 4);
  unsigned int*   subbuf      = (unsigned int*)carve((size_t)NBUC * BCAP * 4);
  int*            row_start   = (int*)carve((size_t)(NN + 1) * 4);
  int*            csr         = (int*)carve((size_t)NETOT * 4);
  unsigned short* h1          = (unsigned short*)carve((size_t)NN * D1 * 2);  // bf16; reused as h2
  float*          als1        = (float*)carve((size_t)NN * H1N * 4);  // reused as als2
  float*          ald1        = (float*)carve((size_t)NN * H1N * 4);  // reused as ald2
  unsigned int*   x1bf        = (unsigned int*)carve((size_t)NN * 32 * 4);  // packed bf16 [N,32]
  unsigned short* h2 = h1; float* als2 = als1; float* ald2 = ald1;

  const int LB = (NN + LNT - 1) / LNT;

  // CSR build: detect -> block-local sort+scatter -> bucket scan -> place
  k_detect<<<1, 64, 0, stream>>>((const long long*)ei, flag);
  (void)hipMemsetAsync(bcnt, 0, (size_t)NBUC * 4, stream);
  k_passA<<<NBLKA, 256, 0, stream>>>(ei, flag, subbuf, bcnt);
  k_bucketsum<<<1, 256, 0, stream>>>(bcnt, bucket_base, row_start);
  k_passB<<<NBUC, 256, 0, stream>>>(bcnt, subbuf, bucket_base, row_start, csr);

  // layer 1
  k_lin1<<<LB, 256, 0, stream>>>(x, W1, as1w, ad1w, h1, als1, ald1);
  k_node1<<<NN / 8, 256, 0, stream>>>(row_start, csr, h1, als1, ald1, b1, x1bf);

  // layer 2
  k_lin2<<<LB, 256, 0, stream>>>(x1bf, W2, as2w, ad2w, h2, als2, ald2);
  k_node2<<<NN / 8, 256, 0, stream>>>(row_start, csr, h2, als2, ald2, b2, out);
}

// Round 12
// 206.185 us; speedup vs baseline: 2.5622x; 1.0565x over previous
//
#include <hip/hip_runtime.h>
#include <math.h>

#define NN 100000
#define NE 1600000
#define NETOT (NE + NN)
#define FIN 128
#define H1N 8
#define D1 64
#define NC 40
#define LNT 64                        // nodes per tile in lin kernels
#define LOG2E 1.44269504088896f

#define BSH 9                         // 512 dst nodes per bucket
#define BNODES 512
#define NBUC ((NN + BNODES - 1) / BNODES)   // 196
#define EPB 4096                      // edges per passA block
#define NBLKA ((NE + EPB - 1) / EPB)  // 391
#define BCAP 9216                     // per-bucket edge capacity (mean 8192, +11 sigma)
#define LB1 ((NN + LNT - 1) / LNT)    // 1563

__device__ __forceinline__ float leakyf(float x) { return x >= 0.0f ? x : 0.2f * x; }
__device__ __forceinline__ float eluf(float x)   { return x > 0.0f ? x : expm1f(x); }
__device__ __forceinline__ float exp2fast(float x) { return __builtin_amdgcn_exp2f(x); }

// bf16 helpers
__device__ __forceinline__ unsigned short f2bf(float f) {
  unsigned u = __float_as_uint(f);
  u += 0x7fffu + ((u >> 16) & 1u);
  return (unsigned short)(u >> 16);
}
__device__ __forceinline__ float bflo(unsigned u) { return __uint_as_float(u << 16); }
__device__ __forceinline__ float bfhi(unsigned u) { return __uint_as_float(u & 0xffff0000u); }

// ---- edge_index dtype detection (int64 vs int32) ------------------------
__global__ void k_detect(const long long* __restrict__ ei, int* __restrict__ flag) {
  if (blockIdx.x == 0 && threadIdx.x == 0) {
    int is64 = 1;
    for (int i = 0; i < 16; ++i) {
      long long v = ei[i];
      if (v < 0 || v >= NN) is64 = 0;
    }
    *flag = is64;
  }
}

// ---- fused: blocks [0,NBLKA) = passA bucket-sort; [NBLKA,+LB1) = lin1 ----
// passA and lin1 are independent (edge_index vs x/W1); fusing removes the
// stream-order full-drain between them. 64KB LDS union, 512 threads.
#define XS1(node, k) xs[(node) * FIN + ((k) ^ ((node) & 31))]
__global__ __launch_bounds__(512) void k_fusedA(
    const void* __restrict__ ei, const int* __restrict__ flag,
    unsigned int* __restrict__ subbuf, int* __restrict__ bcnt,
    const float* __restrict__ x, const float* __restrict__ W,
    const float* __restrict__ aw_s, const float* __restrict__ aw_d,
    unsigned short* __restrict__ h, float* __restrict__ als,
    float* __restrict__ ald) {
  __shared__ __align__(16) char smem[65536];
  int t = threadIdx.x;
  if (blockIdx.x < NBLKA) {
    // ---------------- passA: block-local LDS counting sort ----------------
    unsigned int*   pay    = (unsigned int*)smem;            // 16KB
    unsigned int*   spay   = pay + EPB;                      // 16KB
    unsigned short* bk     = (unsigned short*)(spay + EPB);  // 8KB
    unsigned short* sbk    = bk + EPB;                       // 8KB
    int*            hist   = (int*)(sbk + EPB);              // 1KB
    int*            lstart = hist + 256;                     // 1KB
    int*            cur    = lstart + 256;                   // 1KB
    int*            gbase  = cur + 256;                      // 1KB
    int e0 = blockIdx.x * EPB;
    int cnt = min(EPB, NE - e0);
    if (t < 256) hist[t] = 0;
    __syncthreads();
    bool f64 = (*flag) != 0;
    for (int i = t; i < cnt; i += 512) {
      int s, d;
      if (f64) {
        const long long* p = (const long long*)ei;
        s = (int)p[e0 + i]; d = (int)p[NE + e0 + i];
      } else {
        const int* p = (const int*)ei;
        s = p[e0 + i]; d = p[NE + e0 + i];
      }
      int b = d >> BSH;
      pay[i] = ((unsigned)s << BSH) | (unsigned)(d & (BNODES - 1));
      bk[i] = (unsigned short)b;
      atomicAdd(&hist[b], 1);
    }
    __syncthreads();
    int v = 0;
    if (t < 256) { v = hist[t]; lstart[t] = v; }
    __syncthreads();
    for (int st = 1; st < 256; st <<= 1) {
      int xv = (t < 256 && t >= st) ? lstart[t - st] : 0;
      __syncthreads();
      if (t < 256) lstart[t] += xv;
      __syncthreads();
    }
    int excl = 0;
    if (t < 256) excl = lstart[t] - v;
    __syncthreads();
    if (t < 256) {
      lstart[t] = excl;
      cur[t] = excl;
      gbase[t] = (v > 0) ? atomicAdd(&bcnt[t], v) : 0;
    }
    __syncthreads();
    for (int i = t; i < cnt; i += 512) {
      int b = bk[i];
      int pos = atomicAdd(&cur[b], 1);
      spay[pos] = pay[i];
      sbk[pos] = (unsigned short)b;
    }
    __syncthreads();
    for (int i = t; i < cnt; i += 512) {
      int b = sbk[i];
      int o = gbase[b] + (i - lstart[b]);
      if (o < BCAP) subbuf[(size_t)b * BCAP + o] = spay[i];
    }
  } else {
    // ---------------- lin1: LDS-tiled GEMM, 1 node x 8 cols / thread ------
    float* ws = (float*)smem;            // 32KB [128][64]
    float* xs = ws + FIN * D1;           // 32KB [64][128] swizzled
    int base = (blockIdx.x - NBLKA) * LNT;
    for (int i = t; i < FIN * D1; i += 512) ws[i] = W[i];
    for (int i = t; i < LNT * FIN; i += 512) {
      int node = i >> 7, k = i & 127;
      int gn = base + node;
      if (gn >= NN) gn = NN - 1;
      XS1(node, k) = x[(size_t)gn * FIN + k];
    }
    __syncthreads();
    int head = t & 7, nl = t >> 3;       // nl in 0..63
    float acc[8] = {0, 0, 0, 0, 0, 0, 0, 0};
    #pragma unroll 4
    for (int k = 0; k < FIN; ++k) {
      float x0 = XS1(nl, k);
      const float4* wr = (const float4*)&ws[k * D1 + head * 8];
      float4 wa = wr[0], wb = wr[1];
      acc[0] = fmaf(x0, wa.x, acc[0]);
      acc[1] = fmaf(x0, wa.y, acc[1]);
      acc[2] = fmaf(x0, wa.z, acc[2]);
      acc[3] = fmaf(x0, wa.w, acc[3]);
      acc[4] = fmaf(x0, wb.x, acc[4]);
      acc[5] = fmaf(x0, wb.y, acc[5]);
      acc[6] = fmaf(x0, wb.z, acc[6]);
      acc[7] = fmaf(x0, wb.w, acc[7]);
    }
    int n0 = base + nl;
    if (n0 < NN) {
      float s = 0.f, d = 0.f;
      #pragma unroll
      for (int c = 0; c < 8; ++c) {
        h[(size_t)n0 * D1 + head * 8 + c] = f2bf(acc[c]);
        s = fmaf(acc[c], aw_s[head * 8 + c], s);
        d = fmaf(acc[c], aw_d[head * 8 + c], d);
      }
      als[n0 * H1N + head] = s * LOG2E;
      ald[n0 * H1N + head] = d * LOG2E;
    }
  }
}

// ---- bucket totals -> exclusive scan -> bucket_base ----------------------
__global__ void k_bucketsum(const int* __restrict__ bcnt, int* __restrict__ bucket_base,
                            int* __restrict__ row_start) {
  __shared__ int sh[256];
  int t = threadIdx.x;
  int tot = 0;
  if (t < NBUC) {
    int d0 = t << BSH;
    int nloc = min(BNODES, NN - d0);
    tot = nloc + min(bcnt[t], BCAP);
  }
  sh[t] = tot;
  __syncthreads();
  for (int s = 1; s < 256; s <<= 1) {
    int x = (t >= s) ? sh[t - s] : 0;
    __syncthreads();
    sh[t] += x;
    __syncthreads();
  }
  if (t < NBUC) bucket_base[t] = sh[t] - tot;
  if (t == NBUC - 1) row_start[NN] = sh[t];
}

// ---- pass B: per-bucket LDS hist -> scan -> row_start + placement --------
__global__ __launch_bounds__(256) void k_passB(const int* __restrict__ bcnt,
                       const unsigned int* __restrict__ subbuf,
                       const int* __restrict__ bucket_base,
                       int* __restrict__ row_start, int* __restrict__ csr) {
  __shared__ int hist[BNODES];
  __shared__ int ps[256];
  __shared__ int cur[BNODES];
  int b = blockIdx.x, t = threadIdx.x;
  int d0 = b << BSH;
  int nloc = min(BNODES, NN - d0);
  hist[t] = 0; hist[t + 256] = 0;
  __syncthreads();
  int cnt = min(bcnt[b], BCAP);
  const unsigned int* sb = subbuf + (size_t)b * BCAP;
  for (int i = t; i < cnt; i += 256)
    atomicAdd(&hist[sb[i] & (BNODES - 1)], 1);
  __syncthreads();
  int j0 = 2 * t, j1 = 2 * t + 1;
  int s0 = (j0 < nloc) ? hist[j0] + 1 : 0;
  int s1 = (j1 < nloc) ? hist[j1] + 1 : 0;
  int pairsum = s0 + s1;
  ps[t] = pairsum;
  __syncthreads();
  for (int s = 1; s < 256; s <<= 1) {
    int x = (t >= s) ? ps[t - s] : 0;
    __syncthreads();
    ps[t] += x;
    __syncthreads();
  }
  int excl = ps[t] - pairsum + bucket_base[b];
  if (j0 < nloc) {
    row_start[d0 + j0] = excl;
    csr[excl] = d0 + j0;
    cur[j0] = excl + 1;
  }
  if (j1 < nloc) {
    int rs = excl + s0;
    row_start[d0 + j1] = rs;
    csr[rs] = d0 + j1;
    cur[j1] = rs + 1;
  }
  __syncthreads();
  for (int i = t; i < cnt; i += 256) {
    unsigned u = sb[i];
    int pos = atomicAdd(&cur[u & (BNODES - 1)], 1);
    csr[pos] = (int)(u >> BSH);
  }
}

// ---- layer 2 linear: 512 threads, reads packed-bf16 x1; h2 bf16 ----------
#define XS2(node, k) xs[(node) * D1 + ((k) ^ ((node) & 31))]
__global__ __launch_bounds__(512) void k_lin2(
    const unsigned int* __restrict__ x1bf, const float* __restrict__ W,
    const float* __restrict__ aw_s, const float* __restrict__ aw_d,
    unsigned short* __restrict__ h, float* __restrict__ als,
    float* __restrict__ ald) {
  __shared__ float ws[D1 * D1];        // 16KB (zero-padded [64][64])
  __shared__ float xs[LNT * D1];       // 16KB
  int t = threadIdx.x;
  int base = blockIdx.x * LNT;
  for (int i = t; i < D1 * D1; i += 512) {
    int k = i >> 6, c = i & 63;
    ws[i] = (c < NC) ? W[k * NC + c] : 0.f;
  }
  for (int i = t; i < LNT * 32; i += 512) {
    int node = i >> 5, kd = i & 31;
    int gn = base + node;
    if (gn >= NN) gn = NN - 1;
    unsigned u = x1bf[(size_t)gn * 32 + kd];
    XS2(node, 2 * kd)     = bflo(u);
    XS2(node, 2 * kd + 1) = bfhi(u);
  }
  __syncthreads();
  int g = t & 7, nl = t >> 3;          // nl in 0..63, same node = 8 adjacent lanes
  float acc[8] = {0, 0, 0, 0, 0, 0, 0, 0};
  #pragma unroll 4
  for (int k = 0; k < D1; ++k) {
    float x0 = XS2(nl, k);
    const float4* wr = (const float4*)&ws[k * D1 + g * 8];
    float4 wa = wr[0], wb = wr[1];
    acc[0] = fmaf(x0, wa.x, acc[0]);
    acc[1] = fmaf(x0, wa.y, acc[1]);
    acc[2] = fmaf(x0, wa.z, acc[2]);
    acc[3] = fmaf(x0, wa.w, acc[3]);
    acc[4] = fmaf(x0, wb.x, acc[4]);
    acc[5] = fmaf(x0, wb.y, acc[5]);
    acc[6] = fmaf(x0, wb.z, acc[6]);
    acc[7] = fmaf(x0, wb.w, acc[7]);
  }
  int n0 = base + nl;
  float s = 0.f, d = 0.f;
  #pragma unroll
  for (int c = 0; c < 8; ++c) {
    int col = g * 8 + c;
    float aws = (col < NC) ? aw_s[col] : 0.f;
    float awd = (col < NC) ? aw_d[col] : 0.f;
    s = fmaf(acc[c], aws, s);
    d = fmaf(acc[c], awd, d);
  }
  s += __shfl_xor(s, 1); d += __shfl_xor(d, 1);
  s += __shfl_xor(s, 2); d += __shfl_xor(d, 2);
  s += __shfl_xor(s, 4); d += __shfl_xor(d, 4);
  if (n0 < NN) {
    if (g < 5) {
      #pragma unroll
      for (int c = 0; c < 8; ++c) h[(size_t)n0 * NC + g * 8 + c] = f2bf(acc[c]);
    }
    if (g == 0) { als[n0] = s * LOG2E; ald[n0] = d * LOG2E; }
  }
}

// ---- layer 1 aggregate: 2 nodes/wave, independent 32-lane halves ---------
__global__ void k_node1(const int* __restrict__ row_start, const int* __restrict__ csr,
                        const unsigned short* __restrict__ h, const float* __restrict__ als,
                        const float* __restrict__ ald, const float* __restrict__ b,
                        unsigned int* __restrict__ x1bf) {
  __shared__ float pl[4][2][32 * 9];
  int wid = threadIdx.x >> 6, half = (threadIdx.x >> 5) & 1, c2 = threadIdx.x & 31;
  int n = blockIdx.x * 8 + wid * 2 + half;          // NN % 8 == 0
  float* pw = pl[wid][half];
  const unsigned int* h32 = (const unsigned int*)h;
  int r0 = row_start[n], r1 = row_start[n + 1];
  int hd = c2 >> 2;
  const float4* adp = (const float4*)(ald + (size_t)n * H1N);
  float4 ad0 = adp[0], ad1 = adp[1];
  float S = 0.f;
  float alo0 = 0.f, ahi0 = 0.f, alo1 = 0.f, ahi1 = 0.f;
  float alo2 = 0.f, ahi2 = 0.f, alo3 = 0.f, ahi3 = 0.f;
  for (int kb = r0; kb < r1; kb += 32) {
    int cnt = min(32, r1 - kb);
    if (c2 < cnt) {
      int sk = csr[kb + c2];
      const float4* ap = (const float4*)(als + (size_t)sk * H1N);
      float4 a0 = ap[0], a1 = ap[1];
      pw[c2 * 9 + 0] = exp2fast(leakyf(a0.x + ad0.x));
      pw[c2 * 9 + 1] = exp2fast(leakyf(a0.y + ad0.y));
      pw[c2 * 9 + 2] = exp2fast(leakyf(a0.z + ad0.z));
      pw[c2 * 9 + 3] = exp2fast(leakyf(a0.w + ad0.w));
      pw[c2 * 9 + 4] = exp2fast(leakyf(a1.x + ad1.x));
      pw[c2 * 9 + 5] = exp2fast(leakyf(a1.y + ad1.y));
      pw[c2 * 9 + 6] = exp2fast(leakyf(a1.z + ad1.z));
      pw[c2 * 9 + 7] = exp2fast(leakyf(a1.w + ad1.w));
      pw[c2 * 9 + 8] = __int_as_float(sk);
    }
    asm volatile("s_waitcnt lgkmcnt(0)" ::: "memory");   // wave-internal LDS RAW
    int j = 0;
    for (; j + 4 <= cnt; j += 4) {
      int s0 = __float_as_int(pw[(j + 0) * 9 + 8]);
      int s1 = __float_as_int(pw[(j + 1) * 9 + 8]);
      int s2 = __float_as_int(pw[(j + 2) * 9 + 8]);
      int s3 = __float_as_int(pw[(j + 3) * 9 + 8]);
      float p0 = pw[(j + 0) * 9 + hd], p1 = pw[(j + 1) * 9 + hd];
      float p2 = pw[(j + 2) * 9 + hd], p3 = pw[(j + 3) * 9 + hd];
      unsigned u0 = h32[(unsigned)s0 * 32 + c2];
      unsigned u1 = h32[(unsigned)s1 * 32 + c2];
      unsigned u2 = h32[(unsigned)s2 * 32 + c2];
      unsigned u3 = h32[(unsigned)s3 * 32 + c2];
      alo0 = fmaf(p0, bflo(u0), alo0); ahi0 = fmaf(p0, bfhi(u0), ahi0);
      alo1 = fmaf(p1, bflo(u1), alo1); ahi1 = fmaf(p1, bfhi(u1), ahi1);
      alo2 = fmaf(p2, bflo(u2), alo2); ahi2 = fmaf(p2, bfhi(u2), ahi2);
      alo3 = fmaf(p3, bflo(u3), alo3); ahi3 = fmaf(p3, bfhi(u3), ahi3);
      S += (p0 + p1) + (p2 + p3);
    }
    for (; j < cnt; ++j) {
      int s0 = __float_as_int(pw[j * 9 + 8]);
      float p0 = pw[j * 9 + hd];
      unsigned u0 = h32[(unsigned)s0 * 32 + c2];
      alo0 = fmaf(p0, bflo(u0), alo0); ahi0 = fmaf(p0, bfhi(u0), ahi0);
      S += p0;
    }
  }
  float alo = (alo0 + alo1) + (alo2 + alo3);
  float ahi = (ahi0 + ahi1) + (ahi2 + ahi3);
  float inv = 1.0f / (S + 1e-16f);
  float ox = eluf(alo * inv + b[2 * c2 + 0]);
  float oy = eluf(ahi * inv + b[2 * c2 + 1]);
  x1bf[(size_t)n * 32 + c2] = (unsigned)f2bf(ox) | ((unsigned)f2bf(oy) << 16);
}

// ---- layer 2 aggregate: 2 nodes/wave halves; fp32 output -----------------
__global__ void k_node2(const int* __restrict__ row_start, const int* __restrict__ csr,
                        const unsigned short* __restrict__ h, const float* __restrict__ als,
                        const float* __restrict__ ald, const float* __restrict__ b,
                        float* __restrict__ out) {
  __shared__ float pl[4][2][32 * 3];
  int wid = threadIdx.x >> 6, half = (threadIdx.x >> 5) & 1, c2 = threadIdx.x & 31;
  int n = blockIdx.x * 8 + wid * 2 + half;
  float* pw = pl[wid][half];
  const unsigned int* h32 = (const unsigned int*)h;
  int r0 = row_start[n], r1 = row_start[n + 1];
  int cl = c2 < 20 ? c2 : 19;
  float aldn = ald[n];
  float S = 0.f;
  float alo0 = 0.f, ahi0 = 0.f, alo1 = 0.f, ahi1 = 0.f;
  float alo2 = 0.f, ahi2 = 0.f, alo3 = 0.f, ahi3 = 0.f;
  for (int kb = r0; kb < r1; kb += 32) {
    int cnt = min(32, r1 - kb);
    if (c2 < cnt) {
      int sk = csr[kb + c2];
      pw[c2 * 3 + 0] = exp2fast(leakyf(als[sk] + aldn));
      pw[c2 * 3 + 1] = __int_as_float(sk);
    }
    asm volatile("s_waitcnt lgkmcnt(0)" ::: "memory");
    int j = 0;
    for (; j + 4 <= cnt; j += 4) {
      int s0 = __float_as_int(pw[(j + 0) * 3 + 1]);
      int s1 = __float_as_int(pw[(j + 1) * 3 + 1]);
      int s2 = __float_as_int(pw[(j + 2) * 3 + 1]);
      int s3 = __float_as_int(pw[(j + 3) * 3 + 1]);
      float p0 = pw[(j + 0) * 3], p1 = pw[(j + 1) * 3];
      float p2 = pw[(j + 2) * 3], p3 = pw[(j + 3) * 3];
      unsigned u0 = h32[(unsigned)s0 * 20 + cl];
      unsigned u1 = h32[(unsigned)s1 * 20 + cl];
      unsigned u2 = h32[(unsigned)s2 * 20 + cl];
      unsigned u3 = h32[(unsigned)s3 * 20 + cl];
      alo0 = fmaf(p0, bflo(u0), alo0); ahi0 = fmaf(p0, bfhi(u0), ahi0);
      alo1 = fmaf(p1, bflo(u1), alo1); ahi1 = fmaf(p1, bfhi(u1), ahi1);
      alo2 = fmaf(p2, bflo(u2), alo2); ahi2 = fmaf(p2, bfhi(u2), ahi2);
      alo3 = fmaf(p3, bflo(u3), alo3); ahi3 = fmaf(p3, bfhi(u3), ahi3);
      S += (p0 + p1) + (p2 + p3);
    }
    for (; j < cnt; ++j) {
      int s0 = __float_as_int(pw[j * 3 + 1]);
      float p0 = pw[j * 3];
      unsigned u0 = h32[(unsigned)s0 * 20 + cl];
      alo0 = fmaf(p0, bflo(u0), alo0); ahi0 = fmaf(p0, bfhi(u0), ahi0);
      S += p0;
    }
  }
  float alo = (alo0 + alo1) + (alo2 + alo3);
  float ahi = (ahi0 + ahi1) + (ahi2 + ahi3);
  if (c2 < 20) {
    float inv = 1.0f / (S + 1e-16f);
    float2 o;
    o.x = eluf(alo * inv + b[2 * c2 + 0]);
    o.y = eluf(ahi * inv + b[2 * c2 + 1]);
    ((float2*)out)[(size_t)n * 20 + c2] = o;
  }
}

extern "C" void kernel_launch(void* const* d_in, const int* in_sizes, int n_in,
                              void* d_out, int out_size, void* d_ws, size_t ws_size,
                              hipStream_t stream) {
  const float* x    = (const float*)d_in[0];
  const void*  ei   = d_in[1];
  const float* W1   = (const float*)d_in[3];
  const float* as1w = (const float*)d_in[4];
  const float* ad1w = (const float*)d_in[5];
  const float* b1   = (const float*)d_in[6];
  const float* W2   = (const float*)d_in[7];
  const float* as2w = (const float*)d_in[8];
  const float* ad2w = (const float*)d_in[9];
  const float* b2   = (const float*)d_in[10];
  float* out = (float*)d_out;

  char* w = (char*)d_ws;
  size_t off = 0;
  auto carve = [&](size_t bytes) -> void* {
    void* r = w + off;
    off += (bytes + 255) & ~(size_t)255;
    return r;
  };
  int*            flag        = (int*)carve(256);
  int*            bcnt        = (int*)carve((size_t)NBUC * 4);
  int*            bucket_base = (int*)carve((size_t)NBUC * 4);
  unsigned int*   subbuf      = (unsigned int*)carve((size_t)NBUC * BCAP * 4);
  int*            row_start   = (int*)carve((size_t)(NN + 1) * 4);
  int*            csr         = (int*)carve((size_t)NETOT * 4);
  unsigned short* h1          = (unsigned short*)carve((size_t)NN * D1 * 2);  // bf16; reused as h2
  float*          als1        = (float*)carve((size_t)NN * H1N * 4);  // reused as als2
  float*          ald1        = (float*)carve((size_t)NN * H1N * 4);  // reused as ald2
  unsigned int*   x1bf        = (unsigned int*)carve((size_t)NN * 32 * 4);  // packed bf16 [N,32]
  unsigned short* h2 = h1; float* als2 = als1; float* ald2 = ald1;

  // detect + zero counters
  k_detect<<<1, 64, 0, stream>>>((const long long*)ei, flag);
  (void)hipMemsetAsync(bcnt, 0, (size_t)NBUC * 4, stream);

  // fused: passA bucket-sort + lin1 GEMM (independent work, one dispatch)
  k_fusedA<<<NBLKA + LB1, 512, 0, stream>>>(ei, flag, subbuf, bcnt,
                                            x, W1, as1w, ad1w, h1, als1, ald1);

  // CSR finalize
  k_bucketsum<<<1, 256, 0, stream>>>(bcnt, bucket_base, row_start);
  k_passB<<<NBUC, 256, 0, stream>>>(bcnt, subbuf, bucket_base, row_start, csr);

  // layer 1 aggregate
  k_node1<<<NN / 8, 256, 0, stream>>>(row_start, csr, h1, als1, ald1, b1, x1bf);

  // layer 2
  k_lin2<<<LB1, 512, 0, stream>>>(x1bf, W2, as2w, ad2w, h2, als2, ald2);
  k_node2<<<NN / 8, 256, 0, stream>>>(row_start, csr, h2, als2, ald2, b2, out);
}